// Round 1
// baseline (1357.088 us; speedup 1.0000x reference)
//
#include <hip/hip_runtime.h>
#include <math.h>

#define B_   16
#define C_   1536
#define N_   1024
#define M_   64
#define L_   128
#define G_   256
#define HID_ 512

// ---------------------------------------------------------------------------
// Generic tiled fp32 GEMM:  C[b][o][n] = act( sum_k A[o][k] * Bm[b][k][n] + bias[o] )
// A: [O][K] row-major, Bm: per-b [K][1024] row-major, C: per-b [O][1024].
// 64x64 tile, KT=16, 256 threads, 4x4 per thread.
// ---------------------------------------------------------------------------
template<int O, int K, bool RELU>
__global__ __launch_bounds__(256) void gemm_kernel(
    const float* __restrict__ A, const float* __restrict__ Bm,
    const float* __restrict__ bias, float* __restrict__ Cm,
    long strideB, long strideC)
{
    __shared__ float As[16][68];   // padded: write banks (4kk+oo)%32 -> 2-way (free)
    __shared__ float Bs[16][64];
    const int t  = threadIdx.x;
    const int tx = t & 15, ty = t >> 4;
    const int n0 = blockIdx.x * 64;
    const int o0 = blockIdx.y * 64;
    const float* Bb = Bm + (long)blockIdx.z * strideB;
    float*       Cb = Cm + (long)blockIdx.z * strideC;

    float acc[4][4] = {};

    for (int k0 = 0; k0 < K; k0 += 16) {
        #pragma unroll
        for (int i = 0; i < 4; ++i) {
            int idx = t + i * 256;
            int kk = idx & 15, oo = idx >> 4;
            As[kk][oo] = A[(long)(o0 + oo) * K + (k0 + kk)];
            int nn = idx & 63, kb = idx >> 6;
            Bs[kb][nn] = Bb[(long)(k0 + kb) * N_ + (n0 + nn)];
        }
        __syncthreads();
        #pragma unroll
        for (int kk = 0; kk < 16; ++kk) {
            float4 av = *(const float4*)&As[kk][ty * 4];
            float4 bv = *(const float4*)&Bs[kk][tx * 4];
            float a_[4] = {av.x, av.y, av.z, av.w};
            float b_[4] = {bv.x, bv.y, bv.z, bv.w};
            #pragma unroll
            for (int i = 0; i < 4; ++i)
                #pragma unroll
                for (int j = 0; j < 4; ++j)
                    acc[i][j] = fmaf(a_[i], b_[j], acc[i][j]);
        }
        __syncthreads();
    }

    #pragma unroll
    for (int i = 0; i < 4; ++i) {
        int o = o0 + ty * 4 + i;
        float bz = bias[o];
        float4 ov;
        float v0 = acc[i][0] + bz, v1 = acc[i][1] + bz,
              v2 = acc[i][2] + bz, v3 = acc[i][3] + bz;
        if (RELU) { v0 = fmaxf(v0, 0.f); v1 = fmaxf(v1, 0.f);
                    v2 = fmaxf(v2, 0.f); v3 = fmaxf(v3, 0.f); }
        ov.x = v0; ov.y = v1; ov.z = v2; ov.w = v3;
        *(float4*)&Cb[(long)o * N_ + n0 + tx * 4] = ov;
    }
}

// ---------------------------------------------------------------------------
// Global token head: tok = relu(t @ Wt1^T + bt1) @ Wt2^T + bt2; tok_n = l2norm(tok)
// one block per batch, 256 threads.
// ---------------------------------------------------------------------------
__global__ __launch_bounds__(256) void token_kernel(
    const float* __restrict__ t_in, const float* __restrict__ Wt1,
    const float* __restrict__ bt1,  const float* __restrict__ Wt2,
    const float* __restrict__ bt2,  float* __restrict__ tokn)
{
    __shared__ float tb[C_];
    __shared__ float hid[HID_];
    __shared__ float red[4];
    const int b = blockIdx.x, t = threadIdx.x;

    for (int i = t; i < C_; i += 256) tb[i] = t_in[b * C_ + i];
    __syncthreads();
    for (int o = t; o < HID_; o += 256) {
        float acc = bt1[o];
        const float* wr = Wt1 + (long)o * C_;
        for (int c = 0; c < C_; ++c) acc = fmaf(tb[c], wr[c], acc);
        hid[o] = fmaxf(acc, 0.f);
    }
    __syncthreads();
    float g = bt2[t];
    {
        const float* wr = Wt2 + (long)t * HID_;
        for (int o = 0; o < HID_; ++o) g = fmaf(hid[o], wr[o], g);
    }
    float ss = g * g;
    for (int off = 32; off; off >>= 1) ss += __shfl_down(ss, off);
    if ((t & 63) == 0) red[t >> 6] = ss;
    __syncthreads();
    float tot = red[0] + red[1] + red[2] + red[3];
    float inv = 1.f / fmaxf(sqrtf(tot), 1e-12f);
    tokn[b * G_ + t] = g * inv;
}

// ---------------------------------------------------------------------------
// Sinkhorn OT (3 iters) on p [B, 64, 1024] with dust-bin row = alpha.
// One block per batch, 1024 threads (16 waves). In-place: p -> P = exp(Z).
// ---------------------------------------------------------------------------
__global__ __launch_bounds__(1024) void sinkhorn_kernel(
    float* __restrict__ p, const float* __restrict__ dust)
{
    __shared__ float v_s[N_];
    __shared__ float u_s[M_ + 1];
    const int b = blockIdx.x, t = threadIdx.x;
    const int lane = t & 63, w = t >> 6;
    const float alpha = dust[0];
    const float norm = -logf((float)(M_ + N_));       // -log(1088)
    const float logmu_top = logf((float)N_) + norm;
    float* pb = p + (long)b * M_ * N_;

    v_s[t] = 0.f;
    __syncthreads();

    for (int it = 0; it < 3; ++it) {
        // ---- u update: per row m, logsumexp over n of (Z0[m,n] + v[n]) ----
        for (int m = w; m < M_ + 1; m += 16) {
            float mx = -1e30f, s = 0.f;
            for (int i = 0; i < 16; ++i) {
                int n = i * 64 + lane;
                float z = (m < M_) ? pb[(long)m * N_ + n] : alpha;
                float val = z + v_s[n];
                if (val > mx) { s = s * expf(mx - val) + 1.f; mx = val; }
                else          { s += expf(val - mx); }
            }
            for (int off = 1; off < 64; off <<= 1) {
                float omx = __shfl_xor(mx, off);
                float os  = __shfl_xor(s,  off);
                if (omx > mx) { s = s * expf(mx - omx) + os; mx = omx; }
                else          { s += os * expf(omx - mx); }
            }
            if (lane == 0)
                u_s[m] = ((m < M_) ? norm : logmu_top) - (mx + logf(s));
        }
        __syncthreads();
        // ---- v update: per col n (=t), logsumexp over m of (Z0[m,n] + u[m]) ----
        {
            float mx = -1e30f, s = 0.f;
            for (int m = 0; m < M_ + 1; ++m) {
                float z = (m < M_) ? pb[(long)m * N_ + t] : alpha;
                float val = z + u_s[m];
                if (val > mx) { s = s * expf(mx - val) + 1.f; mx = val; }
                else          { s += expf(val - mx); }
            }
            v_s[t] = norm - (mx + logf(s));
        }
        __syncthreads();
    }
    // ---- P = exp(Z0 + u + v - norm), rows 0..63 only, in-place ----
    for (int idx = t; idx < M_ * N_; idx += 1024) {
        int m = idx >> 10, n = idx & 1023;
        pb[idx] = expf(pb[idx] + u_s[m] + v_s[n] - norm);
    }
}

// ---------------------------------------------------------------------------
// Per-(b,n): column inv-norm of f over L, T_i = softplus(f . Wtp + btp);
// also zeroes discount accumulator.
// ---------------------------------------------------------------------------
__global__ __launch_bounds__(256) void tnorm_kernel(
    const float* __restrict__ f, const float* __restrict__ Wtp,
    const float* __restrict__ btp, float* __restrict__ invn,
    float* __restrict__ T, float* __restrict__ draw)
{
    const int id = blockIdx.x * 256 + threadIdx.x;   // b*1024 + n
    const int b = id >> 10, n = id & 1023;
    const float* fb = f + (long)b * L_ * N_ + n;
    float ss = 0.f, dot = 0.f;
    for (int l = 0; l < L_; ++l) {
        float v = fb[(long)l * N_];
        ss  = fmaf(v, v, ss);
        dot = fmaf(v, Wtp[l], dot);
    }
    invn[id] = 1.f / fmaxf(sqrtf(ss), 1e-12f);
    float x = dot + btp[0];
    T[id] = (x > 0.f) ? (x + log1pf(expf(-x))) : log1pf(expf(x));
    draw[id] = 0.f;
}

// ---------------------------------------------------------------------------
// Fused sim + burst weighting row-sum: draw[b][i] += sum_j sigmoid(Tavg*sim + bb)
// tiles 64x64, K=128 chunked by 64 to stay under 64 KB LDS.
// ---------------------------------------------------------------------------
__global__ __launch_bounds__(256) void sim_kernel(
    const float* __restrict__ f, const float* __restrict__ invn,
    const float* __restrict__ T, const float* __restrict__ bb,
    float* __restrict__ draw)
{
    __shared__ float Fi[64][64];
    __shared__ float Fj[64][64];
    __shared__ float Tii[64], Tjj[64], inni[64], innj[64], rows[64];
    const int b = blockIdx.z, i0 = blockIdx.y * 64, j0 = blockIdx.x * 64;
    const int t = threadIdx.x, tx = t & 15, ty = t >> 4;
    const float burstb = bb[0];

    if (t < 64) {
        Tii[t]  = T[b * N_ + i0 + t];
        Tjj[t]  = T[b * N_ + j0 + t];
        inni[t] = invn[b * N_ + i0 + t];
        innj[t] = invn[b * N_ + j0 + t];
        rows[t] = 0.f;
    }
    __syncthreads();

    const float* fb = f + (long)b * L_ * N_;
    float acc[4][4] = {};
    for (int l0 = 0; l0 < L_; l0 += 64) {
        for (int idx = t; idx < 64 * 64; idx += 256) {
            int l = idx >> 6, c = idx & 63;
            Fi[l][c] = fb[(long)(l0 + l) * N_ + i0 + c] * inni[c];
            Fj[l][c] = fb[(long)(l0 + l) * N_ + j0 + c] * innj[c];
        }
        __syncthreads();
        #pragma unroll 8
        for (int l = 0; l < 64; ++l) {
            float4 av = *(const float4*)&Fi[l][ty * 4];
            float4 bv = *(const float4*)&Fj[l][tx * 4];
            float a_[4] = {av.x, av.y, av.z, av.w};
            float b_[4] = {bv.x, bv.y, bv.z, bv.w};
            #pragma unroll
            for (int i = 0; i < 4; ++i)
                #pragma unroll
                for (int j = 0; j < 4; ++j)
                    acc[i][j] = fmaf(a_[i], b_[j], acc[i][j]);
        }
        __syncthreads();
    }

    float pr[4] = {};
    #pragma unroll
    for (int i = 0; i < 4; ++i) {
        float Ti = Tii[ty * 4 + i];
        #pragma unroll
        for (int j = 0; j < 4; ++j) {
            float x = 0.5f * (Ti + Tjj[tx * 4 + j]) * acc[i][j] + burstb;
            pr[i] += 1.f / (1.f + expf(-x));
        }
    }
    #pragma unroll
    for (int i = 0; i < 4; ++i) atomicAdd(&rows[ty * 4 + i], pr[i]);
    __syncthreads();
    if (t < 64) atomicAdd(&draw[b * N_ + i0 + t], rows[t]);
}

// ---------------------------------------------------------------------------
// w[b,n] = (1-lam) + lam / (clip(draw^p, 1e-3, 1e3) + 1e-6); also zeroes agg.
// ---------------------------------------------------------------------------
__global__ __launch_bounds__(256) void wn_kernel(
    const float* __restrict__ draw, const float* __restrict__ bp,
    const float* __restrict__ lamd, float* __restrict__ wn,
    float* __restrict__ agg)
{
    const int id = blockIdx.x * 256 + threadIdx.x;   // b*1024 + n
    float d = powf(draw[id], bp[0]);
    d = fminf(fmaxf(d, 1e-3f), 1e3f);
    float lam = 1.f / (1.f + expf(-lamd[0]));
    wn[id] = (1.f - lam) + lam / (d + 1e-6f);
    for (int i = id; i < B_ * L_ * M_; i += B_ * N_) agg[i] = 0.f;
}

// ---------------------------------------------------------------------------
// agg[b][l][m] = sum_n f[b][l][n] * w[b][n] * P[b][m][n]; n chunked by 64,
// partials via global atomicAdd. grid (16 nchunks, 16 b).
// ---------------------------------------------------------------------------
__global__ __launch_bounds__(256) void agg_kernel(
    const float* __restrict__ f, const float* __restrict__ P,
    const float* __restrict__ wn, float* __restrict__ agg)
{
    __shared__ float fch[L_][65];
    __shared__ float Pch[M_][65];
    const int b = blockIdx.y, n0 = blockIdx.x * 64;
    const int t = threadIdx.x, tx = t & 15, ty = t >> 4;
    const float* fb = f + (long)b * L_ * N_;
    const float* Pb = P + (long)b * M_ * N_;
    const float* wb = wn + b * N_;

    for (int idx = t; idx < L_ * 64; idx += 256) {
        int l = idx >> 6, c = idx & 63;
        fch[l][c] = fb[(long)l * N_ + n0 + c];
    }
    for (int idx = t; idx < M_ * 64; idx += 256) {
        int m = idx >> 6, c = idx & 63;
        Pch[m][c] = Pb[(long)m * N_ + n0 + c] * wb[n0 + c];
    }
    __syncthreads();

    float acc[8][4] = {};
    for (int n = 0; n < 64; ++n) {
        float fv[8], pv[4];
        #pragma unroll
        for (int i = 0; i < 8; ++i) fv[i] = fch[ty + 16 * i][n];
        #pragma unroll
        for (int j = 0; j < 4; ++j) pv[j] = Pch[tx * 4 + j][n];
        #pragma unroll
        for (int i = 0; i < 8; ++i)
            #pragma unroll
            for (int j = 0; j < 4; ++j)
                acc[i][j] = fmaf(fv[i], pv[j], acc[i][j]);
    }
    #pragma unroll
    for (int i = 0; i < 8; ++i)
        #pragma unroll
        for (int j = 0; j < 4; ++j)
            atomicAdd(&agg[((long)b * L_ + (ty + 16 * i)) * M_ + tx * 4 + j],
                      acc[i][j]);
}

// ---------------------------------------------------------------------------
// Final: per-cluster l2norm over L, concat [tok_n, agg_n], global l2norm.
// one block per batch.
// ---------------------------------------------------------------------------
__global__ __launch_bounds__(256) void final_kernel(
    const float* __restrict__ tokn, const float* __restrict__ agg,
    float* __restrict__ out)
{
    __shared__ float invm[M_];
    __shared__ float red[4];
    __shared__ float s_invtot;
    const int b = blockIdx.x, t = threadIdx.x;
    const float* ab = agg + (long)b * L_ * M_;

    if (t < 64) {
        float ss = 0.f;
        for (int l = 0; l < L_; ++l) {
            float v = ab[l * M_ + t];
            ss = fmaf(v, v, ss);
        }
        invm[t] = 1.f / fmaxf(sqrtf(ss), 1e-12f);
    }
    __syncthreads();

    float part;
    {
        float tn = tokn[b * G_ + t];
        part = tn * tn;
    }
    for (int idx = t; idx < L_ * M_; idx += 256) {
        float v = ab[idx] * invm[idx & 63];
        part = fmaf(v, v, part);
    }
    for (int off = 32; off; off >>= 1) part += __shfl_down(part, off);
    if ((t & 63) == 0) red[t >> 6] = part;
    __syncthreads();
    if (t == 0)
        s_invtot = 1.f / fmaxf(sqrtf(red[0] + red[1] + red[2] + red[3]), 1e-12f);
    __syncthreads();

    const float invtot = s_invtot;
    float* ob = out + (long)b * (G_ + L_ * M_);
    ob[t] = tokn[b * G_ + t] * invtot;
    for (int idx = t; idx < L_ * M_; idx += 256)
        ob[G_ + idx] = ab[idx] * invm[idx & 63] * invtot;
}

// ---------------------------------------------------------------------------
extern "C" void kernel_launch(void* const* d_in, const int* in_sizes, int n_in,
                              void* d_out, int out_size, void* d_ws, size_t ws_size,
                              hipStream_t stream)
{
    const float* x    = (const float*)d_in[0];
    const float* t_in = (const float*)d_in[1];
    const float* Wt1  = (const float*)d_in[2];
    const float* bt1  = (const float*)d_in[3];
    const float* Wt2  = (const float*)d_in[4];
    const float* bt2  = (const float*)d_in[5];
    const float* Wc1  = (const float*)d_in[6];
    const float* bc1  = (const float*)d_in[7];
    const float* Wc2  = (const float*)d_in[8];
    const float* bc2  = (const float*)d_in[9];
    const float* Ws1  = (const float*)d_in[10];
    const float* bs1  = (const float*)d_in[11];
    const float* Ws2  = (const float*)d_in[12];
    const float* bs2  = (const float*)d_in[13];
    const float* Wtp  = (const float*)d_in[14];
    const float* btp  = (const float*)d_in[15];
    const float* dust = (const float*)d_in[16];
    const float* bb   = (const float*)d_in[17];
    const float* bp   = (const float*)d_in[18];
    const float* lamd = (const float*)d_in[19];

    float* ws   = (float*)d_ws;
    float* h    = ws;                      // [B,512,1024]  8388608
    float* f    = h    + 8388608;          // [B,128,1024]  2097152
    float* P    = f    + 2097152;          // [B, 64,1024]  1048576 (p then P)
    float* tokn = P    + 1048576;          // [B,256]          4096
    float* invn = tokn + 4096;             // [B,1024]        16384
    float* T    = invn + 16384;            // [B,1024]        16384
    float* draw = T    + 16384;            // [B,1024]        16384
    float* wgt  = draw + 16384;            // [B,1024]        16384
    float* agg  = wgt  + 16384;            // [B,128,64]     131072
    float* out  = (float*)d_out;

    // h1 = relu(Wc1 @ xf + bc1); f = Wc2 @ h1 + bc2
    gemm_kernel<512,1536,true ><<<dim3(16,8,16),256,0,stream>>>(Wc1, x, bc1, h, (long)C_*N_, (long)HID_*N_);
    gemm_kernel<128, 512,false><<<dim3(16,2,16),256,0,stream>>>(Wc2, h, bc2, f, (long)HID_*N_, (long)L_*N_);
    // h2 = relu(Ws1 @ xf + bs1) (reuse h); p = Ws2 @ h2 + bs2
    gemm_kernel<512,1536,true ><<<dim3(16,8,16),256,0,stream>>>(Ws1, x, bs1, h, (long)C_*N_, (long)HID_*N_);
    gemm_kernel< 64, 512,false><<<dim3(16,1,16),256,0,stream>>>(Ws2, h, bs2, P, (long)HID_*N_, (long)M_*N_);

    token_kernel   <<<16, 256, 0, stream>>>(t_in, Wt1, bt1, Wt2, bt2, tokn);
    sinkhorn_kernel<<<16, 1024, 0, stream>>>(P, dust);
    tnorm_kernel   <<<64, 256, 0, stream>>>(f, Wtp, btp, invn, T, draw);
    sim_kernel     <<<dim3(16,16,16), 256, 0, stream>>>(f, invn, T, bb, draw);
    wn_kernel      <<<64, 256, 0, stream>>>(draw, bp, lamd, wgt, agg);
    agg_kernel     <<<dim3(16,16), 256, 0, stream>>>(f, P, wgt, agg);
    final_kernel   <<<16, 256, 0, stream>>>(tokn, agg, out);
}

// Round 2
// 719.689 us; speedup vs baseline: 1.8857x; 1.8857x over previous
//
#include <hip/hip_runtime.h>
#include <math.h>

#define B_   16
#define C_   1536
#define N_   1024
#define M_   64
#define L_   128
#define G_   256
#define HID_ 512

typedef __attribute__((ext_vector_type(8))) short short8;
typedef __attribute__((ext_vector_type(4))) float floatx4;

// round-to-nearest-even fp32 -> bf16
__device__ __forceinline__ unsigned short f2bf_rne(float x) {
    unsigned u = __float_as_uint(x);
    unsigned r = u + 0x7fffu + ((u >> 16) & 1u);
    return (unsigned short)(r >> 16);
}
// round-half-up packed pair (cheap, hot path)
__device__ __forceinline__ unsigned pack_bf2(float lo, float hi) {
    unsigned a = __float_as_uint(lo) + 0x8000u;
    unsigned b = __float_as_uint(hi) + 0x8000u;
    return (a >> 16) | (b & 0xffff0000u);
}

__device__ __forceinline__ void gl2lds16(const void* g, void* l) {
    __builtin_amdgcn_global_load_lds(
        (const __attribute__((address_space(1))) void*)g,
        (__attribute__((address_space(3))) void*)l, 16, 0, 0);
}

// ---------------------------------------------------------------------------
// Weight cast: Wbf[1024][1536] = stack(Wc1,Ws1) bf16;
// W2[192][1024] = [Wc2 | 0 ; 0 | Ws2] bf16 (zero-padded stack).
// ---------------------------------------------------------------------------
__global__ __launch_bounds__(256) void cast_w_kernel(
    const float* __restrict__ Wc1, const float* __restrict__ Ws1,
    const float* __restrict__ Wc2, const float* __restrict__ Ws2,
    unsigned short* __restrict__ Wbf, unsigned short* __restrict__ W2)
{
    const int T1 = 1024 * 1536;
    int idx = blockIdx.x * 256 + threadIdx.x;
    if (idx < T1) {
        float v = (idx < 512 * 1536) ? Wc1[idx] : Ws1[idx - 512 * 1536];
        Wbf[idx] = f2bf_rne(v);
    } else if (idx < T1 + 192 * 1024) {
        int i2 = idx - T1;
        int row = i2 >> 10, k = i2 & 1023;
        float v = 0.f;
        if (row < 128) { if (k < 512) v = Wc2[row * 512 + k]; }
        else           { if (k >= 512) v = Ws2[(row - 128) * 512 + (k - 512)]; }
        W2[i2] = f2bf_rne(v);
    }
}

// ---------------------------------------------------------------------------
// GEMM1 (bf16 MFMA): hT[b][n][o] = relu(W[o][:] . x[b][:][n] + bias[o])
// W = Wbf [1024][1536] bf16, x fp32 [b][1536][1024]. 128x128 tile, BK=32.
// A staged via global_load_lds; B (x) staged with fused cvt+transpose.
// ---------------------------------------------------------------------------
__global__ __launch_bounds__(256, 2) void gemm1_kernel(
    const unsigned short* __restrict__ Wbf, const float* __restrict__ x,
    const float* __restrict__ bc1, const float* __restrict__ bs1,
    unsigned short* __restrict__ hT)
{
    __shared__ unsigned short As[128 * 32];   // [o][k], 64B row stride
    __shared__ unsigned short Bs[128 * 40];   // [n][k], padded to 80B stride
    const int t = threadIdx.x;
    const int lane = t & 63, w = t >> 6;
    const int n0 = blockIdx.x * 128, o0 = blockIdx.y * 128, b = blockIdx.z;
    const float* xb = x + (long)b * C_ * N_;

    const int wo = (w >> 1) * 64, wn = (w & 1) * 64;
    const int lrow = lane & 15, kgrp = lane >> 4;

    // staging maps
    const int arow = t >> 2, acol = (t & 3) * 8;      // A: glds
    const int nloc = t & 127, kh = (t >> 7) * 16;     // B: transpose

    floatx4 acc[4][4];
    #pragma unroll
    for (int i = 0; i < 4; ++i)
        #pragma unroll
        for (int j = 0; j < 4; ++j) acc[i][j] = (floatx4)0.0f;

    for (int k0 = 0; k0 < C_; k0 += 32) {
        // --- A tile: 128x32 bf16 via global_load_lds (2 x 16B per thread) ---
        #pragma unroll
        for (int r = 0; r < 2; ++r)
            gl2lds16(Wbf + (long)(o0 + r * 64 + arow) * C_ + k0 + acol,
                     (char*)As + r * 4096 + t * 16);
        // --- B tile: x[k0..k0+32][n0..n0+128] -> Bs[n][k] bf16 ---
        float v[16];
        {
            const float* xp = xb + (long)(k0 + kh) * N_ + n0 + nloc;
            #pragma unroll
            for (int kk = 0; kk < 16; ++kk) v[kk] = xp[(long)kk * N_];
        }
        {
            char* bp = (char*)Bs + nloc * 80 + kh * 2;
            #pragma unroll
            for (int j8 = 0; j8 < 4; ++j8) {
                uint2 u;
                u.x = pack_bf2(v[4 * j8 + 0], v[4 * j8 + 1]);
                u.y = pack_bf2(v[4 * j8 + 2], v[4 * j8 + 3]);
                *(uint2*)(bp + j8 * 8) = u;
            }
        }
        __syncthreads();
        // --- fragments + MFMA ---
        short8 af[4], bfr[4];
        #pragma unroll
        for (int i = 0; i < 4; ++i)
            af[i] = *(const short8*)((const char*)As +
                        (wo + i * 16 + lrow) * 64 + kgrp * 16);
        #pragma unroll
        for (int j = 0; j < 4; ++j)
            bfr[j] = *(const short8*)((const char*)Bs +
                        (wn + j * 16 + lrow) * 80 + kgrp * 16);
        #pragma unroll
        for (int i = 0; i < 4; ++i)
            #pragma unroll
            for (int j = 0; j < 4; ++j)
                acc[i][j] = __builtin_amdgcn_mfma_f32_16x16x32_bf16(
                    af[i], bfr[j], acc[i][j], 0, 0, 0);
        __syncthreads();
    }

    // --- epilogue: relu(acc + bias) -> hT[b][n][o] bf16 (8B packed stores) ---
    const float* bias = (o0 < 512) ? bc1 : bs1;
    const int ob = (o0 < 512) ? o0 : o0 - 512;
    #pragma unroll
    for (int i = 0; i < 4; ++i) {
        int orow = wo + i * 16 + kgrp * 4;          // local o in [0,128)
        float b0 = bias[ob + orow + 0], b1 = bias[ob + orow + 1];
        float b2 = bias[ob + orow + 2], b3 = bias[ob + orow + 3];
        #pragma unroll
        for (int j = 0; j < 4; ++j) {
            int n = n0 + wn + j * 16 + lrow;
            float v0 = fmaxf(acc[i][j][0] + b0, 0.f);
            float v1 = fmaxf(acc[i][j][1] + b1, 0.f);
            float v2 = fmaxf(acc[i][j][2] + b2, 0.f);
            float v3 = fmaxf(acc[i][j][3] + b3, 0.f);
            uint2 pk;
            pk.x = ((unsigned)f2bf_rne(v0)) | (((unsigned)f2bf_rne(v1)) << 16);
            pk.y = ((unsigned)f2bf_rne(v2)) | (((unsigned)f2bf_rne(v3)) << 16);
            *(uint2*)&hT[((long)b * N_ + n) * 1024 + o0 + orow] = pk;
        }
    }
}

// ---------------------------------------------------------------------------
// GEMM23 (bf16 MFMA): rows 0-127 -> f[b][128][1024] fp32,
// rows 128-191 -> p[b][64][1024] fp32. A=W2[192][1024], B=hT[b][n][1024].
// 64x128 tile, BK=32, both operands via global_load_lds.
// ---------------------------------------------------------------------------
__global__ __launch_bounds__(256, 2) void gemm23_kernel(
    const unsigned short* __restrict__ W2, const unsigned short* __restrict__ hT,
    const float* __restrict__ bc2, const float* __restrict__ bs2,
    float* __restrict__ f, float* __restrict__ p)
{
    __shared__ unsigned short As[64 * 32];    // 4 KB
    __shared__ unsigned short Bs[128 * 32];   // 8 KB
    const int t = threadIdx.x;
    const int lane = t & 63, w = t >> 6;
    const int n0 = blockIdx.x * 128, o0 = blockIdx.y * 64, b = blockIdx.z;
    const unsigned short* hTb = hT + (long)b * N_ * 1024;

    const int wo = (w >> 1) * 32, wn = (w & 1) * 64;
    const int lrow = lane & 15, kgrp = lane >> 4;
    const int arow = t >> 2, acol = (t & 3) * 8;

    floatx4 acc[2][4];
    #pragma unroll
    for (int i = 0; i < 2; ++i)
        #pragma unroll
        for (int j = 0; j < 4; ++j) acc[i][j] = (floatx4)0.0f;

    for (int k0 = 0; k0 < 1024; k0 += 32) {
        gl2lds16(W2 + (long)(o0 + arow) * 1024 + k0 + acol, (char*)As + t * 16);
        #pragma unroll
        for (int r = 0; r < 2; ++r)
            gl2lds16(hTb + (long)(n0 + r * 64 + arow) * 1024 + k0 + acol,
                     (char*)Bs + r * 4096 + t * 16);
        __syncthreads();
        short8 af[2], bfr[4];
        #pragma unroll
        for (int i = 0; i < 2; ++i)
            af[i] = *(const short8*)((const char*)As +
                        (wo + i * 16 + lrow) * 64 + kgrp * 16);
        #pragma unroll
        for (int j = 0; j < 4; ++j)
            bfr[j] = *(const short8*)((const char*)Bs +
                        (wn + j * 16 + lrow) * 64 + kgrp * 16);
        #pragma unroll
        for (int i = 0; i < 2; ++i)
            #pragma unroll
            for (int j = 0; j < 4; ++j)
                acc[i][j] = __builtin_amdgcn_mfma_f32_16x16x32_bf16(
                    af[i], bfr[j], acc[i][j], 0, 0, 0);
        __syncthreads();
    }

    #pragma unroll
    for (int i = 0; i < 2; ++i) {
        int o = o0 + wo + i * 16 + kgrp * 4;
        #pragma unroll
        for (int j = 0; j < 4; ++j) {
            int n = n0 + wn + j * 16 + lrow;
            #pragma unroll
            for (int r = 0; r < 4; ++r) {
                int oo = o + r;
                float v = acc[i][j][r];
                if (oo < 128) f[((long)b * L_ + oo) * N_ + n] = v + bc2[oo];
                else p[((long)b * M_ + (oo - 128)) * N_ + n] = v + bs2[oo - 128];
            }
        }
    }
}

// ---------------------------------------------------------------------------
// Global token head (unchanged)
// ---------------------------------------------------------------------------
__global__ __launch_bounds__(256) void token_kernel(
    const float* __restrict__ t_in, const float* __restrict__ Wt1,
    const float* __restrict__ bt1,  const float* __restrict__ Wt2,
    const float* __restrict__ bt2,  float* __restrict__ tokn)
{
    __shared__ float tb[C_];
    __shared__ float hid[HID_];
    __shared__ float red[4];
    const int b = blockIdx.x, t = threadIdx.x;

    for (int i = t; i < C_; i += 256) tb[i] = t_in[b * C_ + i];
    __syncthreads();
    for (int o = t; o < HID_; o += 256) {
        float acc = bt1[o];
        const float* wr = Wt1 + (long)o * C_;
        for (int c = 0; c < C_; ++c) acc = fmaf(tb[c], wr[c], acc);
        hid[o] = fmaxf(acc, 0.f);
    }
    __syncthreads();
    float g = bt2[t];
    {
        const float* wr = Wt2 + (long)t * HID_;
        for (int o = 0; o < HID_; ++o) g = fmaf(hid[o], wr[o], g);
    }
    float ss = g * g;
    for (int off = 32; off; off >>= 1) ss += __shfl_down(ss, off);
    if ((t & 63) == 0) red[t >> 6] = ss;
    __syncthreads();
    float tot = red[0] + red[1] + red[2] + red[3];
    float inv = 1.f / fmaxf(sqrtf(tot), 1e-12f);
    tokn[b * G_ + t] = g * inv;
}

// ---------------------------------------------------------------------------
// Sinkhorn OT (unchanged)
// ---------------------------------------------------------------------------
__global__ __launch_bounds__(1024) void sinkhorn_kernel(
    float* __restrict__ p, const float* __restrict__ dust)
{
    __shared__ float v_s[N_];
    __shared__ float u_s[M_ + 1];
    const int b = blockIdx.x, t = threadIdx.x;
    const int lane = t & 63, w = t >> 6;
    const float alpha = dust[0];
    const float norm = -logf((float)(M_ + N_));
    const float logmu_top = logf((float)N_) + norm;
    float* pb = p + (long)b * M_ * N_;

    v_s[t] = 0.f;
    __syncthreads();

    for (int it = 0; it < 3; ++it) {
        for (int m = w; m < M_ + 1; m += 16) {
            float mx = -1e30f, s = 0.f;
            for (int i = 0; i < 16; ++i) {
                int n = i * 64 + lane;
                float z = (m < M_) ? pb[(long)m * N_ + n] : alpha;
                float val = z + v_s[n];
                if (val > mx) { s = s * expf(mx - val) + 1.f; mx = val; }
                else          { s += expf(val - mx); }
            }
            for (int off = 1; off < 64; off <<= 1) {
                float omx = __shfl_xor(mx, off);
                float os  = __shfl_xor(s,  off);
                if (omx > mx) { s = s * expf(mx - omx) + os; mx = omx; }
                else          { s += os * expf(omx - mx); }
            }
            if (lane == 0)
                u_s[m] = ((m < M_) ? norm : logmu_top) - (mx + logf(s));
        }
        __syncthreads();
        {
            float mx = -1e30f, s = 0.f;
            for (int m = 0; m < M_ + 1; ++m) {
                float z = (m < M_) ? pb[(long)m * N_ + t] : alpha;
                float val = z + u_s[m];
                if (val > mx) { s = s * expf(mx - val) + 1.f; mx = val; }
                else          { s += expf(val - mx); }
            }
            v_s[t] = norm - (mx + logf(s));
        }
        __syncthreads();
    }
    for (int idx = t; idx < M_ * N_; idx += 1024) {
        int m = idx >> 10, n = idx & 1023;
        pb[idx] = expf(pb[idx] + u_s[m] + v_s[n] - norm);
    }
}

// ---------------------------------------------------------------------------
// tnorm (unchanged)
// ---------------------------------------------------------------------------
__global__ __launch_bounds__(256) void tnorm_kernel(
    const float* __restrict__ f, const float* __restrict__ Wtp,
    const float* __restrict__ btp, float* __restrict__ invn,
    float* __restrict__ T, float* __restrict__ draw)
{
    const int id = blockIdx.x * 256 + threadIdx.x;
    const int b = id >> 10, n = id & 1023;
    const float* fb = f + (long)b * L_ * N_ + n;
    float ss = 0.f, dot = 0.f;
    for (int l = 0; l < L_; ++l) {
        float v = fb[(long)l * N_];
        ss  = fmaf(v, v, ss);
        dot = fmaf(v, Wtp[l], dot);
    }
    invn[id] = 1.f / fmaxf(sqrtf(ss), 1e-12f);
    float x = dot + btp[0];
    T[id] = (x > 0.f) ? (x + log1pf(expf(-x))) : log1pf(expf(x));
    draw[id] = 0.f;
}

// ---------------------------------------------------------------------------
// sim + burst row-sum (unchanged)
// ---------------------------------------------------------------------------
__global__ __launch_bounds__(256) void sim_kernel(
    const float* __restrict__ f, const float* __restrict__ invn,
    const float* __restrict__ T, const float* __restrict__ bb,
    float* __restrict__ draw)
{
    __shared__ float Fi[64][64];
    __shared__ float Fj[64][64];
    __shared__ float Tii[64], Tjj[64], inni[64], innj[64], rows[64];
    const int b = blockIdx.z, i0 = blockIdx.y * 64, j0 = blockIdx.x * 64;
    const int t = threadIdx.x, tx = t & 15, ty = t >> 4;
    const float burstb = bb[0];

    if (t < 64) {
        Tii[t]  = T[b * N_ + i0 + t];
        Tjj[t]  = T[b * N_ + j0 + t];
        inni[t] = invn[b * N_ + i0 + t];
        innj[t] = invn[b * N_ + j0 + t];
        rows[t] = 0.f;
    }
    __syncthreads();

    const float* fb = f + (long)b * L_ * N_;
    float acc[4][4] = {};
    for (int l0 = 0; l0 < L_; l0 += 64) {
        for (int idx = t; idx < 64 * 64; idx += 256) {
            int l = idx >> 6, c = idx & 63;
            Fi[l][c] = fb[(long)(l0 + l) * N_ + i0 + c] * inni[c];
            Fj[l][c] = fb[(long)(l0 + l) * N_ + j0 + c] * innj[c];
        }
        __syncthreads();
        #pragma unroll 8
        for (int l = 0; l < 64; ++l) {
            float4 av = *(const float4*)&Fi[l][ty * 4];
            float4 bv = *(const float4*)&Fj[l][tx * 4];
            float a_[4] = {av.x, av.y, av.z, av.w};
            float b_[4] = {bv.x, bv.y, bv.z, bv.w};
            #pragma unroll
            for (int i = 0; i < 4; ++i)
                #pragma unroll
                for (int j = 0; j < 4; ++j)
                    acc[i][j] = fmaf(a_[i], b_[j], acc[i][j]);
        }
        __syncthreads();
    }

    float pr[4] = {};
    #pragma unroll
    for (int i = 0; i < 4; ++i) {
        float Ti = Tii[ty * 4 + i];
        #pragma unroll
        for (int j = 0; j < 4; ++j) {
            float x = 0.5f * (Ti + Tjj[tx * 4 + j]) * acc[i][j] + burstb;
            pr[i] += 1.f / (1.f + expf(-x));
        }
    }
    #pragma unroll
    for (int i = 0; i < 4; ++i) atomicAdd(&rows[ty * 4 + i], pr[i]);
    __syncthreads();
    if (t < 64) atomicAdd(&draw[b * N_ + i0 + t], rows[t]);
}

// ---------------------------------------------------------------------------
// wn (unchanged)
// ---------------------------------------------------------------------------
__global__ __launch_bounds__(256) void wn_kernel(
    const float* __restrict__ draw, const float* __restrict__ bp,
    const float* __restrict__ lamd, float* __restrict__ wn,
    float* __restrict__ agg)
{
    const int id = blockIdx.x * 256 + threadIdx.x;
    float d = powf(draw[id], bp[0]);
    d = fminf(fmaxf(d, 1e-3f), 1e3f);
    float lam = 1.f / (1.f + expf(-lamd[0]));
    wn[id] = (1.f - lam) + lam / (d + 1e-6f);
    for (int i = id; i < B_ * L_ * M_; i += B_ * N_) agg[i] = 0.f;
}

// ---------------------------------------------------------------------------
// agg (unchanged)
// ---------------------------------------------------------------------------
__global__ __launch_bounds__(256) void agg_kernel(
    const float* __restrict__ f, const float* __restrict__ P,
    const float* __restrict__ wn, float* __restrict__ agg)
{
    __shared__ float fch[L_][65];
    __shared__ float Pch[M_][65];
    const int b = blockIdx.y, n0 = blockIdx.x * 64;
    const int t = threadIdx.x, tx = t & 15, ty = t >> 4;
    const float* fb = f + (long)b * L_ * N_;
    const float* Pb = P + (long)b * M_ * N_;
    const float* wb = wn + b * N_;

    for (int idx = t; idx < L_ * 64; idx += 256) {
        int l = idx >> 6, c = idx & 63;
        fch[l][c] = fb[(long)l * N_ + n0 + c];
    }
    for (int idx = t; idx < M_ * 64; idx += 256) {
        int m = idx >> 6, c = idx & 63;
        Pch[m][c] = Pb[(long)m * N_ + n0 + c] * wb[n0 + c];
    }
    __syncthreads();

    float acc[8][4] = {};
    for (int n = 0; n < 64; ++n) {
        float fv[8], pv[4];
        #pragma unroll
        for (int i = 0; i < 8; ++i) fv[i] = fch[ty + 16 * i][n];
        #pragma unroll
        for (int j = 0; j < 4; ++j) pv[j] = Pch[tx * 4 + j][n];
        #pragma unroll
        for (int i = 0; i < 8; ++i)
            #pragma unroll
            for (int j = 0; j < 4; ++j)
                acc[i][j] = fmaf(fv[i], pv[j], acc[i][j]);
    }
    #pragma unroll
    for (int i = 0; i < 8; ++i)
        #pragma unroll
        for (int j = 0; j < 4; ++j)
            atomicAdd(&agg[((long)b * L_ + (ty + 16 * i)) * M_ + tx * 4 + j],
                      acc[i][j]);
}

// ---------------------------------------------------------------------------
// final (unchanged)
// ---------------------------------------------------------------------------
__global__ __launch_bounds__(256) void final_kernel(
    const float* __restrict__ tokn, const float* __restrict__ agg,
    float* __restrict__ out)
{
    __shared__ float invm[M_];
    __shared__ float red[4];
    __shared__ float s_invtot;
    const int b = blockIdx.x, t = threadIdx.x;
    const float* ab = agg + (long)b * L_ * M_;

    if (t < 64) {
        float ss = 0.f;
        for (int l = 0; l < L_; ++l) {
            float v = ab[l * M_ + t];
            ss = fmaf(v, v, ss);
        }
        invm[t] = 1.f / fmaxf(sqrtf(ss), 1e-12f);
    }
    __syncthreads();

    float part;
    {
        float tn = tokn[b * G_ + t];
        part = tn * tn;
    }
    for (int idx = t; idx < L_ * M_; idx += 256) {
        float v = ab[idx] * invm[idx & 63];
        part = fmaf(v, v, part);
    }
    for (int off = 32; off; off >>= 1) part += __shfl_down(part, off);
    if ((t & 63) == 0) red[t >> 6] = part;
    __syncthreads();
    if (t == 0)
        s_invtot = 1.f / fmaxf(sqrtf(red[0] + red[1] + red[2] + red[3]), 1e-12f);
    __syncthreads();

    const float invtot = s_invtot;
    float* ob = out + (long)b * (G_ + L_ * M_);
    ob[t] = tokn[b * G_ + t] * invtot;
    for (int idx = t; idx < L_ * M_; idx += 256)
        ob[G_ + idx] = ab[idx] * invm[idx & 63] * invtot;
}

// ---------------------------------------------------------------------------
extern "C" void kernel_launch(void* const* d_in, const int* in_sizes, int n_in,
                              void* d_out, int out_size, void* d_ws, size_t ws_size,
                              hipStream_t stream)
{
    const float* x    = (const float*)d_in[0];
    const float* t_in = (const float*)d_in[1];
    const float* Wt1  = (const float*)d_in[2];
    const float* bt1  = (const float*)d_in[3];
    const float* Wt2  = (const float*)d_in[4];
    const float* bt2  = (const float*)d_in[5];
    const float* Wc1  = (const float*)d_in[6];
    const float* bc1  = (const float*)d_in[7];
    const float* Wc2  = (const float*)d_in[8];
    const float* bc2  = (const float*)d_in[9];
    const float* Ws1  = (const float*)d_in[10];
    const float* bs1  = (const float*)d_in[11];
    const float* Ws2  = (const float*)d_in[12];
    const float* bs2  = (const float*)d_in[13];
    const float* Wtp  = (const float*)d_in[14];
    const float* btp  = (const float*)d_in[15];
    const float* dust = (const float*)d_in[16];
    const float* bb   = (const float*)d_in[17];
    const float* bp   = (const float*)d_in[18];
    const float* lamd = (const float*)d_in[19];

    char* wsb = (char*)d_ws;
    unsigned short* hT  = (unsigned short*)wsb;                 // 33,554,432 B
    unsigned short* Wbf = (unsigned short*)(wsb + 33554432);    //  3,145,728 B
    unsigned short* W2  = (unsigned short*)(wsb + 36700160);    //    393,216 B
    float* f    = (float*)(wsb + 37093376);                     //  8,388,608 B
    float* P    = (float*)(wsb + 45481984);                     //  4,194,304 B
    float* tokn = (float*)(wsb + 49676288);                     //     16,384 B
    float* invn = (float*)(wsb + 49692672);                     //     65,536 B
    float* T    = (float*)(wsb + 49758208);                     //     65,536 B
    float* draw = (float*)(wsb + 49823744);                     //     65,536 B
    float* wgt  = (float*)(wsb + 49889280);                     //     65,536 B
    float* agg  = (float*)(wsb + 49954816);                     //    524,288 B
    float* out  = (float*)d_out;

    cast_w_kernel<<<6912, 256, 0, stream>>>(Wc1, Ws1, Wc2, Ws2, Wbf, W2);
    gemm1_kernel <<<dim3(8, 8, 16), 256, 0, stream>>>(Wbf, x, bc1, bs1, hT);
    gemm23_kernel<<<dim3(8, 3, 16), 256, 0, stream>>>(W2, hT, bc2, bs2, f, P);

    token_kernel   <<<16, 256, 0, stream>>>(t_in, Wt1, bt1, Wt2, bt2, tokn);
    sinkhorn_kernel<<<16, 1024, 0, stream>>>(P, dust);
    tnorm_kernel   <<<64, 256, 0, stream>>>(f, Wtp, btp, invn, T, draw);
    sim_kernel     <<<dim3(16, 16, 16), 256, 0, stream>>>(f, invn, T, bb, draw);
    wn_kernel      <<<64, 256, 0, stream>>>(draw, bp, lamd, wgt, agg);
    agg_kernel     <<<dim3(16, 16), 256, 0, stream>>>(f, P, wgt, agg);
    final_kernel   <<<16, 256, 0, stream>>>(tokn, agg, out);
}

// Round 3
// 506.856 us; speedup vs baseline: 2.6775x; 1.4199x over previous
//
#include <hip/hip_runtime.h>
#include <math.h>

#define B_   16
#define C_   1536
#define N_   1024
#define M_   64
#define L_   128
#define G_   256
#define HID_ 512

typedef __attribute__((ext_vector_type(8))) short short8;
typedef __attribute__((ext_vector_type(4))) float floatx4;

// round-to-nearest-even fp32 -> bf16
__device__ __forceinline__ unsigned short f2bf_rne(float x) {
    unsigned u = __float_as_uint(x);
    unsigned r = u + 0x7fffu + ((u >> 16) & 1u);
    return (unsigned short)(r >> 16);
}
// round-half-up packed pair (cheap, hot path)
__device__ __forceinline__ unsigned pack_bf2(float lo, float hi) {
    unsigned a = __float_as_uint(lo) + 0x8000u;
    unsigned b = __float_as_uint(hi) + 0x8000u;
    return (a >> 16) | (b & 0xffff0000u);
}

__device__ __forceinline__ void gl2lds16(const void* g, void* l) {
    __builtin_amdgcn_global_load_lds(
        (const __attribute__((address_space(1))) void*)g,
        (__attribute__((address_space(3))) void*)l, 16, 0, 0);
}

// ---------------------------------------------------------------------------
// Weight cast: Wbf[1024][1536] = stack(Wc1,Ws1) bf16;
// W2[192][1024] = [Wc2 | 0 ; 0 | Ws2] bf16 (zero-padded stack).
// ---------------------------------------------------------------------------
__global__ __launch_bounds__(256) void cast_w_kernel(
    const float* __restrict__ Wc1, const float* __restrict__ Ws1,
    const float* __restrict__ Wc2, const float* __restrict__ Ws2,
    unsigned short* __restrict__ Wbf, unsigned short* __restrict__ W2)
{
    const int T1 = 1024 * 1536;
    int idx = blockIdx.x * 256 + threadIdx.x;
    if (idx < T1) {
        float v = (idx < 512 * 1536) ? Wc1[idx] : Ws1[idx - 512 * 1536];
        Wbf[idx] = f2bf_rne(v);
    } else if (idx < T1 + 192 * 1024) {
        int i2 = idx - T1;
        int row = i2 >> 10, k = i2 & 1023;
        float v = 0.f;
        if (row < 128) { if (k < 512) v = Wc2[row * 512 + k]; }
        else           { if (k >= 512) v = Ws2[(row - 128) * 512 + (k - 512)]; }
        W2[i2] = f2bf_rne(v);
    }
}

// ---------------------------------------------------------------------------
// GEMM1 (bf16 MFMA): hT[b][n][o] = relu(W[o][:] . x[b][:][n] + bias[o])
// ---------------------------------------------------------------------------
__global__ __launch_bounds__(256, 2) void gemm1_kernel(
    const unsigned short* __restrict__ Wbf, const float* __restrict__ x,
    const float* __restrict__ bc1, const float* __restrict__ bs1,
    unsigned short* __restrict__ hT)
{
    __shared__ unsigned short As[128 * 32];   // [o][k], 64B row stride
    __shared__ unsigned short Bs[128 * 40];   // [n][k], padded to 80B stride
    const int t = threadIdx.x;
    const int lane = t & 63, w = t >> 6;
    const int n0 = blockIdx.x * 128, o0 = blockIdx.y * 128, b = blockIdx.z;
    const float* xb = x + (long)b * C_ * N_;

    const int wo = (w >> 1) * 64, wn = (w & 1) * 64;
    const int lrow = lane & 15, kgrp = lane >> 4;

    const int arow = t >> 2, acol = (t & 3) * 8;
    const int nloc = t & 127, kh = (t >> 7) * 16;

    floatx4 acc[4][4];
    #pragma unroll
    for (int i = 0; i < 4; ++i)
        #pragma unroll
        for (int j = 0; j < 4; ++j) acc[i][j] = (floatx4)0.0f;

    for (int k0 = 0; k0 < C_; k0 += 32) {
        #pragma unroll
        for (int r = 0; r < 2; ++r)
            gl2lds16(Wbf + (long)(o0 + r * 64 + arow) * C_ + k0 + acol,
                     (char*)As + r * 4096 + t * 16);
        float v[16];
        {
            const float* xp = xb + (long)(k0 + kh) * N_ + n0 + nloc;
            #pragma unroll
            for (int kk = 0; kk < 16; ++kk) v[kk] = xp[(long)kk * N_];
        }
        {
            char* bp = (char*)Bs + nloc * 80 + kh * 2;
            #pragma unroll
            for (int j8 = 0; j8 < 4; ++j8) {
                uint2 u;
                u.x = pack_bf2(v[4 * j8 + 0], v[4 * j8 + 1]);
                u.y = pack_bf2(v[4 * j8 + 2], v[4 * j8 + 3]);
                *(uint2*)(bp + j8 * 8) = u;
            }
        }
        __syncthreads();
        short8 af[4], bfr[4];
        #pragma unroll
        for (int i = 0; i < 4; ++i)
            af[i] = *(const short8*)((const char*)As +
                        (wo + i * 16 + lrow) * 64 + kgrp * 16);
        #pragma unroll
        for (int j = 0; j < 4; ++j)
            bfr[j] = *(const short8*)((const char*)Bs +
                        (wn + j * 16 + lrow) * 80 + kgrp * 16);
        #pragma unroll
        for (int i = 0; i < 4; ++i)
            #pragma unroll
            for (int j = 0; j < 4; ++j)
                acc[i][j] = __builtin_amdgcn_mfma_f32_16x16x32_bf16(
                    af[i], bfr[j], acc[i][j], 0, 0, 0);
        __syncthreads();
    }

    const float* bias = (o0 < 512) ? bc1 : bs1;
    const int ob = (o0 < 512) ? o0 : o0 - 512;
    #pragma unroll
    for (int i = 0; i < 4; ++i) {
        int orow = wo + i * 16 + kgrp * 4;
        float b0 = bias[ob + orow + 0], b1 = bias[ob + orow + 1];
        float b2 = bias[ob + orow + 2], b3 = bias[ob + orow + 3];
        #pragma unroll
        for (int j = 0; j < 4; ++j) {
            int n = n0 + wn + j * 16 + lrow;
            float v0 = fmaxf(acc[i][j][0] + b0, 0.f);
            float v1 = fmaxf(acc[i][j][1] + b1, 0.f);
            float v2 = fmaxf(acc[i][j][2] + b2, 0.f);
            float v3 = fmaxf(acc[i][j][3] + b3, 0.f);
            uint2 pk;
            pk.x = ((unsigned)f2bf_rne(v0)) | (((unsigned)f2bf_rne(v1)) << 16);
            pk.y = ((unsigned)f2bf_rne(v2)) | (((unsigned)f2bf_rne(v3)) << 16);
            *(uint2*)&hT[((long)b * N_ + n) * 1024 + o0 + orow] = pk;
        }
    }
}

// ---------------------------------------------------------------------------
// GEMM23 (bf16 MFMA): rows 0-127 -> f fp32, rows 128-191 -> p fp32.
// ---------------------------------------------------------------------------
__global__ __launch_bounds__(256, 2) void gemm23_kernel(
    const unsigned short* __restrict__ W2, const unsigned short* __restrict__ hT,
    const float* __restrict__ bc2, const float* __restrict__ bs2,
    float* __restrict__ f, float* __restrict__ p)
{
    __shared__ unsigned short As[64 * 32];
    __shared__ unsigned short Bs[128 * 32];
    const int t = threadIdx.x;
    const int lane = t & 63, w = t >> 6;
    const int n0 = blockIdx.x * 128, o0 = blockIdx.y * 64, b = blockIdx.z;
    const unsigned short* hTb = hT + (long)b * N_ * 1024;

    const int wo = (w >> 1) * 32, wn = (w & 1) * 64;
    const int lrow = lane & 15, kgrp = lane >> 4;
    const int arow = t >> 2, acol = (t & 3) * 8;

    floatx4 acc[2][4];
    #pragma unroll
    for (int i = 0; i < 2; ++i)
        #pragma unroll
        for (int j = 0; j < 4; ++j) acc[i][j] = (floatx4)0.0f;

    for (int k0 = 0; k0 < 1024; k0 += 32) {
        gl2lds16(W2 + (long)(o0 + arow) * 1024 + k0 + acol, (char*)As + t * 16);
        #pragma unroll
        for (int r = 0; r < 2; ++r)
            gl2lds16(hTb + (long)(n0 + r * 64 + arow) * 1024 + k0 + acol,
                     (char*)Bs + r * 4096 + t * 16);
        __syncthreads();
        short8 af[2], bfr[4];
        #pragma unroll
        for (int i = 0; i < 2; ++i)
            af[i] = *(const short8*)((const char*)As +
                        (wo + i * 16 + lrow) * 64 + kgrp * 16);
        #pragma unroll
        for (int j = 0; j < 4; ++j)
            bfr[j] = *(const short8*)((const char*)Bs +
                        (wn + j * 16 + lrow) * 64 + kgrp * 16);
        #pragma unroll
        for (int i = 0; i < 2; ++i)
            #pragma unroll
            for (int j = 0; j < 4; ++j)
                acc[i][j] = __builtin_amdgcn_mfma_f32_16x16x32_bf16(
                    af[i], bfr[j], acc[i][j], 0, 0, 0);
        __syncthreads();
    }

    #pragma unroll
    for (int i = 0; i < 2; ++i) {
        int o = o0 + wo + i * 16 + kgrp * 4;
        #pragma unroll
        for (int j = 0; j < 4; ++j) {
            int n = n0 + wn + j * 16 + lrow;
            #pragma unroll
            for (int r = 0; r < 4; ++r) {
                int oo = o + r;
                float v = acc[i][j][r];
                if (oo < 128) f[((long)b * L_ + oo) * N_ + n] = v + bc2[oo];
                else p[((long)b * M_ + (oo - 128)) * N_ + n] = v + bs2[oo - 128];
            }
        }
    }
}

// ---------------------------------------------------------------------------
// Token head: wave-per-output GEMV kernels (coalesced float4 + shuffle reduce)
// ---------------------------------------------------------------------------
__global__ __launch_bounds__(256) void token1_kernel(
    const float* __restrict__ t_in, const float* __restrict__ Wt1,
    const float* __restrict__ bt1, float* __restrict__ hid)
{
    const int lane = threadIdx.x & 63, w = threadIdx.x >> 6;
    const int o = blockIdx.x * 4 + w, b = blockIdx.y;
    const float4* wr = (const float4*)(Wt1 + (long)o * C_);
    const float4* tb = (const float4*)(t_in + (long)b * C_);
    float acc = 0.f;
    #pragma unroll
    for (int i = 0; i < 6; ++i) {
        float4 a = wr[i * 64 + lane], tv = tb[i * 64 + lane];
        acc += a.x * tv.x + a.y * tv.y + a.z * tv.z + a.w * tv.w;
    }
    #pragma unroll
    for (int off = 1; off < 64; off <<= 1) acc += __shfl_xor(acc, off);
    if (lane == 0) hid[b * HID_ + o] = fmaxf(acc + bt1[o], 0.f);
}

__global__ __launch_bounds__(256) void token2_kernel(
    const float* __restrict__ hid, const float* __restrict__ Wt2,
    const float* __restrict__ bt2, float* __restrict__ tok)
{
    const int lane = threadIdx.x & 63, w = threadIdx.x >> 6;
    const int g = blockIdx.x * 4 + w, b = blockIdx.y;
    const float4* wr = (const float4*)(Wt2 + (long)g * HID_);
    const float4* hb = (const float4*)(hid + (long)b * HID_);
    float acc = 0.f;
    #pragma unroll
    for (int i = 0; i < 2; ++i) {
        float4 a = wr[i * 64 + lane], hv = hb[i * 64 + lane];
        acc += a.x * hv.x + a.y * hv.y + a.z * hv.z + a.w * hv.w;
    }
    #pragma unroll
    for (int off = 1; off < 64; off <<= 1) acc += __shfl_xor(acc, off);
    if (lane == 0) tok[b * G_ + g] = acc + bt2[g];
}

__global__ __launch_bounds__(256) void token3_kernel(
    const float* __restrict__ tok, float* __restrict__ tokn)
{
    __shared__ float red[4];
    const int b = blockIdx.x, t = threadIdx.x;
    float v = tok[b * G_ + t];
    float ss = v * v;
    #pragma unroll
    for (int off = 1; off < 64; off <<= 1) ss += __shfl_xor(ss, off);
    if ((t & 63) == 0) red[t >> 6] = ss;
    __syncthreads();
    float inv = 1.f / fmaxf(sqrtf(red[0] + red[1] + red[2] + red[3]), 1e-12f);
    tokn[b * G_ + t] = v * inv;
}

// ---------------------------------------------------------------------------
// Sinkhorn OT: column cached in VGPRs, two-pass (max, then pipelined exps).
// ---------------------------------------------------------------------------
__global__ __launch_bounds__(1024) void sinkhorn_kernel(
    float* __restrict__ p, const float* __restrict__ dust)
{
    __shared__ float v_s[N_];
    __shared__ float u_s[M_ + 1];
    const int b = blockIdx.x, t = threadIdx.x;
    const int lane = t & 63, w = t >> 6;
    const float alpha = dust[0];
    const float norm = -logf((float)(M_ + N_));
    const float logmu_top = logf((float)N_) + norm;
    float* pb = p + (long)b * M_ * N_;

    float z[64];
    #pragma unroll
    for (int m = 0; m < 64; ++m) z[m] = pb[m * N_ + t];

    v_s[t] = 0.f;
    __syncthreads();

    for (int it = 0; it < 3; ++it) {
        // u-update: wave per row, two-pass logsumexp over n
        for (int m = w; m < M_ + 1; m += 16) {
            float zv[16], mx = -1e30f;
            #pragma unroll
            for (int i = 0; i < 16; ++i) {
                int n = i * 64 + lane;
                float val = ((m < M_) ? pb[(long)m * N_ + n] : alpha) + v_s[n];
                zv[i] = val; mx = fmaxf(mx, val);
            }
            #pragma unroll
            for (int off = 1; off < 64; off <<= 1)
                mx = fmaxf(mx, __shfl_xor(mx, off));
            float s = 0.f;
            #pragma unroll
            for (int i = 0; i < 16; ++i) s += expf(zv[i] - mx);
            #pragma unroll
            for (int off = 1; off < 64; off <<= 1) s += __shfl_xor(s, off);
            if (lane == 0)
                u_s[m] = ((m < M_) ? norm : logmu_top) - (mx + logf(s));
        }
        __syncthreads();
        // v-update: thread per column, registers
        float mx = alpha + u_s[M_];
        #pragma unroll
        for (int m = 0; m < 64; ++m) mx = fmaxf(mx, z[m] + u_s[m]);
        float s = expf(alpha + u_s[M_] - mx);
        #pragma unroll
        for (int m = 0; m < 64; ++m) s += expf(z[m] + u_s[m] - mx);
        v_s[t] = norm - (mx + logf(s));
        __syncthreads();
    }
    const float vt = v_s[t];
    #pragma unroll
    for (int m = 0; m < 64; ++m)
        pb[m * N_ + t] = expf(z[m] + u_s[m] + vt - norm);
}

// ---------------------------------------------------------------------------
// tnorm: LDS-tiled. Computes T, zeroes draw, writes fnT[b][n][128] bf16
// (l2-normalized f columns, k-contiguous for sim's MFMA).
// ---------------------------------------------------------------------------
__global__ __launch_bounds__(256) void tnorm_kernel(
    const float* __restrict__ f, const float* __restrict__ Wtp,
    const float* __restrict__ btp, unsigned short* __restrict__ fnT,
    float* __restrict__ T, float* __restrict__ draw)
{
    __shared__ float Ft[L_][65];
    __shared__ float invs[64];
    __shared__ float wtp_s[L_];
    const int b = blockIdx.y, n0 = blockIdx.x * 64, t = threadIdx.x;
    const float* fb = f + (long)b * L_ * N_;

    if (t < L_) wtp_s[t] = Wtp[t];
    for (int it = 0; it < 32; ++it) {
        int idx = it * 256 + t;
        int l = idx >> 6, c = idx & 63;
        Ft[l][c] = fb[(long)l * N_ + n0 + c];
    }
    __syncthreads();
    if (t < 64) {
        float ss = 0.f, dot = 0.f;
        #pragma unroll
        for (int l = 0; l < L_; ++l) {
            float v = Ft[l][t];
            ss = fmaf(v, v, ss);
            dot = fmaf(v, wtp_s[l], dot);
        }
        invs[t] = 1.f / fmaxf(sqrtf(ss), 1e-12f);
        float xx = dot + btp[0];
        T[b * N_ + n0 + t] = (xx > 0.f) ? (xx + log1pf(expf(-xx)))
                                        : log1pf(expf(xx));
        draw[b * N_ + n0 + t] = 0.f;
    }
    __syncthreads();
    unsigned* fo = (unsigned*)fnT;
    for (int it = 0; it < 16; ++it) {
        int idx = it * 256 + t;
        int nl = idx >> 6, jp = idx & 63;
        float inv = invs[nl];
        fo[(((long)b * N_ + n0 + nl) << 6) + jp] =
            pack_bf2(Ft[2 * jp][nl] * inv, Ft[2 * jp + 1][nl] * inv);
    }
}

// ---------------------------------------------------------------------------
// sim (bf16 MFMA): draw[b][i] += sum_j sigmoid(0.5*(Ti+Tj)*(fn_i . fn_j) + bb)
// 64x64 tile, K=128. LDS rows padded to 272 B.
// ---------------------------------------------------------------------------
__global__ __launch_bounds__(256) void sim_kernel(
    const unsigned short* __restrict__ fnT, const float* __restrict__ T,
    const float* __restrict__ bb, float* __restrict__ draw)
{
    __shared__ unsigned short As[64 * 136];
    __shared__ unsigned short Bs[64 * 136];
    __shared__ float Ti[64], Tj[64];
    const int b = blockIdx.z, i0 = blockIdx.y * 64, j0 = blockIdx.x * 64;
    const int t = threadIdx.x, lane = t & 63, w = t >> 6;
    const int lrow = lane & 15, kgrp = lane >> 4;
    const unsigned short* fb = fnT + (long)b * N_ * 128;

    if (t < 64) Ti[t] = T[b * N_ + i0 + t];
    else if (t < 128) Tj[t - 64] = T[b * N_ + j0 + (t - 64)];

    const int srow = t >> 4, scol = (t & 15) * 8;
    #pragma unroll
    for (int r = 0; r < 4; ++r) {
        uint4 av = *(const uint4*)(fb + (long)(i0 + r * 16 + srow) * 128 + scol);
        uint4 bv = *(const uint4*)(fb + (long)(j0 + r * 16 + srow) * 128 + scol);
        *(uint4*)((char*)As + (r * 16 + srow) * 272 + scol * 2) = av;
        *(uint4*)((char*)Bs + (r * 16 + srow) * 272 + scol * 2) = bv;
    }
    __syncthreads();

    floatx4 acc[4];
    #pragma unroll
    for (int j = 0; j < 4; ++j) acc[j] = (floatx4)0.0f;
    #pragma unroll
    for (int k0 = 0; k0 < 128; k0 += 32) {
        short8 af = *(const short8*)((const char*)As +
                        (w * 16 + lrow) * 272 + k0 * 2 + kgrp * 16);
        #pragma unroll
        for (int j = 0; j < 4; ++j) {
            short8 bf = *(const short8*)((const char*)Bs +
                            (j * 16 + lrow) * 272 + k0 * 2 + kgrp * 16);
            acc[j] = __builtin_amdgcn_mfma_f32_16x16x32_bf16(af, bf, acc[j], 0, 0, 0);
        }
    }

    const float burstb = bb[0];
    float rs[4] = {0.f, 0.f, 0.f, 0.f};
    #pragma unroll
    for (int j = 0; j < 4; ++j) {
        float Tjv = Tj[j * 16 + lrow];
        #pragma unroll
        for (int r = 0; r < 4; ++r) {
            float Tiv = Ti[w * 16 + kgrp * 4 + r];
            float xarg = 0.5f * (Tiv + Tjv) * acc[j][r] + burstb;
            rs[r] += 1.f / (1.f + expf(-xarg));
        }
    }
    #pragma unroll
    for (int off = 1; off < 16; off <<= 1)
        #pragma unroll
        for (int r = 0; r < 4; ++r) rs[r] += __shfl_xor(rs[r], off);
    if (lrow == 0) {
        #pragma unroll
        for (int r = 0; r < 4; ++r)
            atomicAdd(&draw[b * N_ + i0 + w * 16 + kgrp * 4 + r], rs[r]);
    }
}

// ---------------------------------------------------------------------------
// wn (unchanged)
// ---------------------------------------------------------------------------
__global__ __launch_bounds__(256) void wn_kernel(
    const float* __restrict__ draw, const float* __restrict__ bp,
    const float* __restrict__ lamd, float* __restrict__ wn,
    float* __restrict__ agg)
{
    const int id = blockIdx.x * 256 + threadIdx.x;
    float d = powf(draw[id], bp[0]);
    d = fminf(fmaxf(d, 1e-3f), 1e3f);
    float lam = 1.f / (1.f + expf(-lamd[0]));
    wn[id] = (1.f - lam) + lam / (d + 1e-6f);
    for (int i = id; i < B_ * L_ * M_; i += B_ * N_) agg[i] = 0.f;
}

// ---------------------------------------------------------------------------
// agg (unchanged)
// ---------------------------------------------------------------------------
__global__ __launch_bounds__(256) void agg_kernel(
    const float* __restrict__ f, const float* __restrict__ P,
    const float* __restrict__ wn, float* __restrict__ agg)
{
    __shared__ float fch[L_][65];
    __shared__ float Pch[M_][65];
    const int b = blockIdx.y, n0 = blockIdx.x * 64;
    const int t = threadIdx.x, tx = t & 15, ty = t >> 4;
    const float* fb = f + (long)b * L_ * N_;
    const float* Pb = P + (long)b * M_ * N_;
    const float* wb = wn + b * N_;

    for (int idx = t; idx < L_ * 64; idx += 256) {
        int l = idx >> 6, c = idx & 63;
        fch[l][c] = fb[(long)l * N_ + n0 + c];
    }
    for (int idx = t; idx < M_ * 64; idx += 256) {
        int m = idx >> 6, c = idx & 63;
        Pch[m][c] = Pb[(long)m * N_ + n0 + c] * wb[n0 + c];
    }
    __syncthreads();

    float acc[8][4] = {};
    for (int n = 0; n < 64; ++n) {
        float fv[8], pv[4];
        #pragma unroll
        for (int i = 0; i < 8; ++i) fv[i] = fch[ty + 16 * i][n];
        #pragma unroll
        for (int j = 0; j < 4; ++j) pv[j] = Pch[tx * 4 + j][n];
        #pragma unroll
        for (int i = 0; i < 8; ++i)
            #pragma unroll
            for (int j = 0; j < 4; ++j)
                acc[i][j] = fmaf(fv[i], pv[j], acc[i][j]);
    }
    #pragma unroll
    for (int i = 0; i < 8; ++i)
        #pragma unroll
        for (int j = 0; j < 4; ++j)
            atomicAdd(&agg[((long)b * L_ + (ty + 16 * i)) * M_ + tx * 4 + j],
                      acc[i][j]);
}

// ---------------------------------------------------------------------------
// final (unchanged)
// ---------------------------------------------------------------------------
__global__ __launch_bounds__(256) void final_kernel(
    const float* __restrict__ tokn, const float* __restrict__ agg,
    float* __restrict__ out)
{
    __shared__ float invm[M_];
    __shared__ float red[4];
    __shared__ float s_invtot;
    const int b = blockIdx.x, t = threadIdx.x;
    const float* ab = agg + (long)b * L_ * M_;

    if (t < 64) {
        float ss = 0.f;
        for (int l = 0; l < L_; ++l) {
            float v = ab[l * M_ + t];
            ss = fmaf(v, v, ss);
        }
        invm[t] = 1.f / fmaxf(sqrtf(ss), 1e-12f);
    }
    __syncthreads();

    float part;
    {
        float tn = tokn[b * G_ + t];
        part = tn * tn;
    }
    for (int idx = t; idx < L_ * M_; idx += 256) {
        float v = ab[idx] * invm[idx & 63];
        part = fmaf(v, v, part);
    }
    for (int off = 32; off; off >>= 1) part += __shfl_down(part, off);
    if ((t & 63) == 0) red[t >> 6] = part;
    __syncthreads();
    if (t == 0)
        s_invtot = 1.f / fmaxf(sqrtf(red[0] + red[1] + red[2] + red[3]), 1e-12f);
    __syncthreads();

    const float invtot = s_invtot;
    float* ob = out + (long)b * (G_ + L_ * M_);
    ob[t] = tokn[b * G_ + t] * invtot;
    for (int idx = t; idx < L_ * M_; idx += 256)
        ob[G_ + idx] = ab[idx] * invm[idx & 63] * invtot;
}

// ---------------------------------------------------------------------------
extern "C" void kernel_launch(void* const* d_in, const int* in_sizes, int n_in,
                              void* d_out, int out_size, void* d_ws, size_t ws_size,
                              hipStream_t stream)
{
    const float* x    = (const float*)d_in[0];
    const float* t_in = (const float*)d_in[1];
    const float* Wt1  = (const float*)d_in[2];
    const float* bt1  = (const float*)d_in[3];
    const float* Wt2  = (const float*)d_in[4];
    const float* bt2  = (const float*)d_in[5];
    const float* Wc1  = (const float*)d_in[6];
    const float* bc1  = (const float*)d_in[7];
    const float* Wc2  = (const float*)d_in[8];
    const float* bc2  = (const float*)d_in[9];
    const float* Ws1  = (const float*)d_in[10];
    const float* bs1  = (const float*)d_in[11];
    const float* Ws2  = (const float*)d_in[12];
    const float* bs2  = (const float*)d_in[13];
    const float* Wtp  = (const float*)d_in[14];
    const float* btp  = (const float*)d_in[15];
    const float* dust = (const float*)d_in[16];
    const float* bb   = (const float*)d_in[17];
    const float* bp   = (const float*)d_in[18];
    const float* lamd = (const float*)d_in[19];

    char* wsb = (char*)d_ws;
    unsigned short* hT  = (unsigned short*)wsb;                 // 33,554,432 B
    // aliased into hT region (dead after gemm23):
    unsigned short* fnT = (unsigned short*)wsb;                 //  4,194,304 B
    float* hid  = (float*)(wsb + 4194304);                      //     32,768 B
    float* tok  = (float*)(wsb + 4227072);                      //     16,384 B
    unsigned short* Wbf = (unsigned short*)(wsb + 33554432);    //  3,145,728 B
    unsigned short* W2  = (unsigned short*)(wsb + 36700160);    //    393,216 B
    float* f    = (float*)(wsb + 37093376);                     //  8,388,608 B
    float* P    = (float*)(wsb + 45481984);                     //  4,194,304 B
    float* tokn = (float*)(wsb + 49676288);                     //     16,384 B
    float* T    = (float*)(wsb + 49692672);                     //     65,536 B
    float* draw = (float*)(wsb + 49758208);                     //     65,536 B
    float* wgt  = (float*)(wsb + 49823744);                     //     65,536 B
    float* agg  = (float*)(wsb + 49889280);                     //    524,288 B
    float* out  = (float*)d_out;

    cast_w_kernel<<<6912, 256, 0, stream>>>(Wc1, Ws1, Wc2, Ws2, Wbf, W2);
    gemm1_kernel <<<dim3(8, 8, 16), 256, 0, stream>>>(Wbf, x, bc1, bs1, hT);
    gemm23_kernel<<<dim3(8, 3, 16), 256, 0, stream>>>(W2, hT, bc2, bs2, f, P);

    // token head (after gemm23: hid/tok alias the dead hT region)
    token1_kernel<<<dim3(128, 16), 256, 0, stream>>>(t_in, Wt1, bt1, hid);
    token2_kernel<<<dim3(64, 16), 256, 0, stream>>>(hid, Wt2, bt2, tok);
    token3_kernel<<<16, 256, 0, stream>>>(tok, tokn);

    sinkhorn_kernel<<<16, 1024, 0, stream>>>(P, dust);
    tnorm_kernel   <<<dim3(16, 16), 256, 0, stream>>>(f, Wtp, btp, fnT, T, draw);
    sim_kernel     <<<dim3(16, 16, 16), 256, 0, stream>>>(fnT, T, bb, draw);
    wn_kernel      <<<64, 256, 0, stream>>>(draw, bp, lamd, wgt, agg);
    agg_kernel     <<<dim3(16, 16), 256, 0, stream>>>(f, P, wgt, agg);
    final_kernel   <<<16, 256, 0, stream>>>(tokn, agg, out);
}

// Round 4
// 409.664 us; speedup vs baseline: 3.3127x; 1.2372x over previous
//
#include <hip/hip_runtime.h>
#include <math.h>

#define B_   16
#define C_   1536
#define N_   1024
#define M_   64
#define L_   128
#define G_   256
#define HID_ 512

typedef __attribute__((ext_vector_type(8))) short short8;
typedef __attribute__((ext_vector_type(4))) float floatx4;

// round-to-nearest-even fp32 -> bf16
__device__ __forceinline__ unsigned short f2bf_rne(float x) {
    unsigned u = __float_as_uint(x);
    unsigned r = u + 0x7fffu + ((u >> 16) & 1u);
    return (unsigned short)(r >> 16);
}
// round-half-up packed pair (cheap, hot path)
__device__ __forceinline__ unsigned pack_bf2(float lo, float hi) {
    unsigned a = __float_as_uint(lo) + 0x8000u;
    unsigned b = __float_as_uint(hi) + 0x8000u;
    return (a >> 16) | (b & 0xffff0000u);
}

__device__ __forceinline__ void gl2lds16(const void* g, void* l) {
    __builtin_amdgcn_global_load_lds(
        (const __attribute__((address_space(1))) void*)g,
        (__attribute__((address_space(3))) void*)l, 16, 0, 0);
}

// ---------------------------------------------------------------------------
// Weight cast: Wbf[1024][1536] = stack(Wc1,Ws1) bf16;
// W2[192][1024] = [Wc2 | 0 ; 0 | Ws2] bf16 (zero-padded stack).
// ---------------------------------------------------------------------------
__global__ __launch_bounds__(256) void cast_w_kernel(
    const float* __restrict__ Wc1, const float* __restrict__ Ws1,
    const float* __restrict__ Wc2, const float* __restrict__ Ws2,
    unsigned short* __restrict__ Wbf, unsigned short* __restrict__ W2)
{
    const int T1 = 1024 * 1536;
    int idx = blockIdx.x * 256 + threadIdx.x;
    if (idx < T1) {
        float v = (idx < 512 * 1536) ? Wc1[idx] : Ws1[idx - 512 * 1536];
        Wbf[idx] = f2bf_rne(v);
    } else if (idx < T1 + 192 * 1024) {
        int i2 = idx - T1;
        int row = i2 >> 10, k = i2 & 1023;
        float v = 0.f;
        if (row < 128) { if (k < 512) v = Wc2[row * 512 + k]; }
        else           { if (k >= 512) v = Ws2[(row - 128) * 512 + (k - 512)]; }
        W2[i2] = f2bf_rne(v);
    }
}

// ---------------------------------------------------------------------------
// Transpose+cast: xT[bl][n][c] bf16 <- x[bofs+bl][c][n] fp32. 64x64 LDS tile.
// ---------------------------------------------------------------------------
__global__ __launch_bounds__(256) void xt_kernel(
    const float* __restrict__ x, unsigned short* __restrict__ xT, int bofs)
{
    __shared__ float Xs[64][65];
    const int t = threadIdx.x;
    const int n0 = blockIdx.x * 64, c0 = blockIdx.y * 64, bl = blockIdx.z;
    const float* xb = x + (long)(bofs + bl) * C_ * N_;
    #pragma unroll
    for (int it = 0; it < 16; ++it) {
        int idx = it * 256 + t, cr = idx >> 6, nc = idx & 63;
        Xs[cr][nc] = xb[(long)(c0 + cr) * N_ + n0 + nc];
    }
    __syncthreads();
    unsigned* xo = (unsigned*)(xT + (long)bl * N_ * C_);
    #pragma unroll
    for (int it = 0; it < 8; ++it) {
        int idx = it * 256 + t, nr = idx >> 5, pc = idx & 31;
        xo[(long)(n0 + nr) * 768 + (c0 >> 1) + pc] =
            pack_bf2(Xs[2 * pc][nr], Xs[2 * pc + 1][nr]);
    }
}

// ---------------------------------------------------------------------------
// GEMM1 (bf16 MFMA, m97 structure): hT[bg][n][o] = relu(W[o] . xT[bl][n] + bias)
// Both operands k-contiguous bf16, staged via global_load_lds dwordx4.
// ---------------------------------------------------------------------------
__global__ __launch_bounds__(256, 2) void gemm1_kernel(
    const unsigned short* __restrict__ Wbf, const unsigned short* __restrict__ xT,
    const float* __restrict__ bc1, const float* __restrict__ bs1,
    unsigned short* __restrict__ hT, int bofs)
{
    __shared__ unsigned short As[128 * 32];
    __shared__ unsigned short Bs[128 * 32];
    const int t = threadIdx.x;
    const int lane = t & 63, w = t >> 6;
    const int n0 = blockIdx.x * 128, o0 = blockIdx.y * 128;
    const int bl = blockIdx.z, bg = bofs + bl;
    const unsigned short* xb = xT + (long)bl * N_ * C_;

    const int wo = (w >> 1) * 64, wn = (w & 1) * 64;
    const int lrow = lane & 15, kgrp = lane >> 4;
    const int arow = t >> 2, acol = (t & 3) * 8;

    floatx4 acc[4][4];
    #pragma unroll
    for (int i = 0; i < 4; ++i)
        #pragma unroll
        for (int j = 0; j < 4; ++j) acc[i][j] = (floatx4)0.0f;

    for (int k0 = 0; k0 < C_; k0 += 32) {
        #pragma unroll
        for (int r = 0; r < 2; ++r)
            gl2lds16(Wbf + (long)(o0 + r * 64 + arow) * C_ + k0 + acol,
                     (char*)As + r * 4096 + t * 16);
        #pragma unroll
        for (int r = 0; r < 2; ++r)
            gl2lds16(xb + (long)(n0 + r * 64 + arow) * C_ + k0 + acol,
                     (char*)Bs + r * 4096 + t * 16);
        __syncthreads();
        short8 af[4], bfr[4];
        #pragma unroll
        for (int i = 0; i < 4; ++i)
            af[i] = *(const short8*)((const char*)As +
                        (wo + i * 16 + lrow) * 64 + kgrp * 16);
        #pragma unroll
        for (int j = 0; j < 4; ++j)
            bfr[j] = *(const short8*)((const char*)Bs +
                        (wn + j * 16 + lrow) * 64 + kgrp * 16);
        #pragma unroll
        for (int i = 0; i < 4; ++i)
            #pragma unroll
            for (int j = 0; j < 4; ++j)
                acc[i][j] = __builtin_amdgcn_mfma_f32_16x16x32_bf16(
                    af[i], bfr[j], acc[i][j], 0, 0, 0);
        __syncthreads();
    }

    const float* bias = (o0 < 512) ? bc1 : bs1;
    const int ob = (o0 < 512) ? o0 : o0 - 512;
    #pragma unroll
    for (int i = 0; i < 4; ++i) {
        int orow = wo + i * 16 + kgrp * 4;
        float b0 = bias[ob + orow + 0], b1 = bias[ob + orow + 1];
        float b2 = bias[ob + orow + 2], b3 = bias[ob + orow + 3];
        #pragma unroll
        for (int j = 0; j < 4; ++j) {
            int n = n0 + wn + j * 16 + lrow;
            float v0 = fmaxf(acc[i][j][0] + b0, 0.f);
            float v1 = fmaxf(acc[i][j][1] + b1, 0.f);
            float v2 = fmaxf(acc[i][j][2] + b2, 0.f);
            float v3 = fmaxf(acc[i][j][3] + b3, 0.f);
            uint2 pk;
            pk.x = ((unsigned)f2bf_rne(v0)) | (((unsigned)f2bf_rne(v1)) << 16);
            pk.y = ((unsigned)f2bf_rne(v2)) | (((unsigned)f2bf_rne(v3)) << 16);
            *(uint2*)&hT[((long)bg * N_ + n) * 1024 + o0 + orow] = pk;
        }
    }
}

// ---------------------------------------------------------------------------
// GEMM23 (bf16 MFMA): rows 0-127 -> f fp32, rows 128-191 -> p fp32.
// ---------------------------------------------------------------------------
__global__ __launch_bounds__(256, 2) void gemm23_kernel(
    const unsigned short* __restrict__ W2, const unsigned short* __restrict__ hT,
    const float* __restrict__ bc2, const float* __restrict__ bs2,
    float* __restrict__ f, float* __restrict__ p)
{
    __shared__ unsigned short As[64 * 32];
    __shared__ unsigned short Bs[128 * 32];
    const int t = threadIdx.x;
    const int lane = t & 63, w = t >> 6;
    const int n0 = blockIdx.x * 128, o0 = blockIdx.y * 64, b = blockIdx.z;
    const unsigned short* hTb = hT + (long)b * N_ * 1024;

    const int wo = (w >> 1) * 32, wn = (w & 1) * 64;
    const int lrow = lane & 15, kgrp = lane >> 4;
    const int arow = t >> 2, acol = (t & 3) * 8;

    floatx4 acc[2][4];
    #pragma unroll
    for (int i = 0; i < 2; ++i)
        #pragma unroll
        for (int j = 0; j < 4; ++j) acc[i][j] = (floatx4)0.0f;

    for (int k0 = 0; k0 < 1024; k0 += 32) {
        gl2lds16(W2 + (long)(o0 + arow) * 1024 + k0 + acol, (char*)As + t * 16);
        #pragma unroll
        for (int r = 0; r < 2; ++r)
            gl2lds16(hTb + (long)(n0 + r * 64 + arow) * 1024 + k0 + acol,
                     (char*)Bs + r * 4096 + t * 16);
        __syncthreads();
        short8 af[2], bfr[4];
        #pragma unroll
        for (int i = 0; i < 2; ++i)
            af[i] = *(const short8*)((const char*)As +
                        (wo + i * 16 + lrow) * 64 + kgrp * 16);
        #pragma unroll
        for (int j = 0; j < 4; ++j)
            bfr[j] = *(const short8*)((const char*)Bs +
                        (wn + j * 16 + lrow) * 64 + kgrp * 16);
        #pragma unroll
        for (int i = 0; i < 2; ++i)
            #pragma unroll
            for (int j = 0; j < 4; ++j)
                acc[i][j] = __builtin_amdgcn_mfma_f32_16x16x32_bf16(
                    af[i], bfr[j], acc[i][j], 0, 0, 0);
        __syncthreads();
    }

    #pragma unroll
    for (int i = 0; i < 2; ++i) {
        int o = o0 + wo + i * 16 + kgrp * 4;
        #pragma unroll
        for (int j = 0; j < 4; ++j) {
            int n = n0 + wn + j * 16 + lrow;
            #pragma unroll
            for (int r = 0; r < 4; ++r) {
                int oo = o + r;
                float v = acc[i][j][r];
                if (oo < 128) f[((long)b * L_ + oo) * N_ + n] = v + bc2[oo];
                else p[((long)b * M_ + (oo - 128)) * N_ + n] = v + bs2[oo - 128];
            }
        }
    }
}

// ---------------------------------------------------------------------------
// Token head: wave-per-output GEMV kernels
// ---------------------------------------------------------------------------
__global__ __launch_bounds__(256) void token1_kernel(
    const float* __restrict__ t_in, const float* __restrict__ Wt1,
    const float* __restrict__ bt1, float* __restrict__ hid)
{
    const int lane = threadIdx.x & 63, w = threadIdx.x >> 6;
    const int o = blockIdx.x * 4 + w, b = blockIdx.y;
    const float4* wr = (const float4*)(Wt1 + (long)o * C_);
    const float4* tb = (const float4*)(t_in + (long)b * C_);
    float acc = 0.f;
    #pragma unroll
    for (int i = 0; i < 6; ++i) {
        float4 a = wr[i * 64 + lane], tv = tb[i * 64 + lane];
        acc += a.x * tv.x + a.y * tv.y + a.z * tv.z + a.w * tv.w;
    }
    #pragma unroll
    for (int off = 1; off < 64; off <<= 1) acc += __shfl_xor(acc, off);
    if (lane == 0) hid[b * HID_ + o] = fmaxf(acc + bt1[o], 0.f);
}

__global__ __launch_bounds__(256) void token2_kernel(
    const float* __restrict__ hid, const float* __restrict__ Wt2,
    const float* __restrict__ bt2, float* __restrict__ tok)
{
    const int lane = threadIdx.x & 63, w = threadIdx.x >> 6;
    const int g = blockIdx.x * 4 + w, b = blockIdx.y;
    const float4* wr = (const float4*)(Wt2 + (long)g * HID_);
    const float4* hb = (const float4*)(hid + (long)b * HID_);
    float acc = 0.f;
    #pragma unroll
    for (int i = 0; i < 2; ++i) {
        float4 a = wr[i * 64 + lane], hv = hb[i * 64 + lane];
        acc += a.x * hv.x + a.y * hv.y + a.z * hv.z + a.w * hv.w;
    }
    #pragma unroll
    for (int off = 1; off < 64; off <<= 1) acc += __shfl_xor(acc, off);
    if (lane == 0) tok[b * G_ + g] = acc + bt2[g];
}

__global__ __launch_bounds__(256) void token3_kernel(
    const float* __restrict__ tok, float* __restrict__ tokn)
{
    __shared__ float red[4];
    const int b = blockIdx.x, t = threadIdx.x;
    float v = tok[b * G_ + t];
    float ss = v * v;
    #pragma unroll
    for (int off = 1; off < 64; off <<= 1) ss += __shfl_xor(ss, off);
    if ((t & 63) == 0) red[t >> 6] = ss;
    __syncthreads();
    float inv = 1.f / fmaxf(sqrtf(red[0] + red[1] + red[2] + red[3]), 1e-12f);
    tokn[b * G_ + t] = v * inv;
}

// ---------------------------------------------------------------------------
// Linear-domain Sinkhorn. K = exp(p) (dust row = exp(alpha)), mu/nu = 1/1088
// (dust mu = 1024/1088). a = mu/(K b); b = nu/(K^T a). P = 1088 a K b (in agg).
// ---------------------------------------------------------------------------
template<bool FIRST>
__global__ __launch_bounds__(256) void ku_kernel(
    const float* __restrict__ p, const float* __restrict__ dust,
    const float* __restrict__ bvec, float* __restrict__ avec)
{
    const int t = threadIdx.x, lane = t & 63, w = t >> 6;
    const int m = blockIdx.x * 4 + w, b = blockIdx.y;
    if (m > M_) return;
    const float* bv = bvec + b * N_;
    float s = 0.f;
    if (m < M_) {
        const float* row = p + ((long)b * M_ + m) * N_;
        #pragma unroll
        for (int i = 0; i < 16; ++i) {
            int n = i * 64 + lane;
            float K = expf(row[n]);
            s += FIRST ? K : K * bv[n];
        }
    } else {
        float ea = expf(dust[0]);
        if (FIRST) s = 16.f * ea;
        else {
            #pragma unroll
            for (int i = 0; i < 16; ++i) s += bv[i * 64 + lane];
            s *= ea;
        }
    }
    #pragma unroll
    for (int off = 1; off < 64; off <<= 1) s += __shfl_xor(s, off);
    if (lane == 0) {
        float mu = (m < M_) ? (1.f / 1088.f) : (1024.f / 1088.f);
        avec[b * (M_ + 1) + m] = mu / s;
    }
}

__global__ __launch_bounds__(256) void kv_kernel(
    const float* __restrict__ p, const float* __restrict__ dust,
    const float* __restrict__ avec, float* __restrict__ bvec)
{
    __shared__ float a_s[M_ + 1];
    const int t = threadIdx.x, b = blockIdx.y;
    const int n = blockIdx.x * 256 + t;
    if (t < M_ + 1) a_s[t] = avec[b * (M_ + 1) + t];
    __syncthreads();
    float s = expf(dust[0]) * a_s[M_];
    const float* col = p + (long)b * M_ * N_ + n;
    #pragma unroll
    for (int m = 0; m < M_; ++m) s = fmaf(expf(col[(long)m * N_]), a_s[m], s);
    bvec[b * N_ + n] = (1.f / 1088.f) / s;
}

// ---------------------------------------------------------------------------
// tnorm: computes T, zeroes draw, writes fnT[b][n][128] bf16 (l2-normalized).
// ---------------------------------------------------------------------------
__global__ __launch_bounds__(256) void tnorm_kernel(
    const float* __restrict__ f, const float* __restrict__ Wtp,
    const float* __restrict__ btp, unsigned short* __restrict__ fnT,
    float* __restrict__ T, float* __restrict__ draw)
{
    __shared__ float Ft[L_][65];
    __shared__ float invs[64];
    __shared__ float wtp_s[L_];
    const int b = blockIdx.y, n0 = blockIdx.x * 64, t = threadIdx.x;
    const float* fb = f + (long)b * L_ * N_;

    if (t < L_) wtp_s[t] = Wtp[t];
    for (int it = 0; it < 32; ++it) {
        int idx = it * 256 + t;
        int l = idx >> 6, c = idx & 63;
        Ft[l][c] = fb[(long)l * N_ + n0 + c];
    }
    __syncthreads();
    if (t < 64) {
        float ss = 0.f, dot = 0.f;
        #pragma unroll
        for (int l = 0; l < L_; ++l) {
            float v = Ft[l][t];
            ss = fmaf(v, v, ss);
            dot = fmaf(v, wtp_s[l], dot);
        }
        invs[t] = 1.f / fmaxf(sqrtf(ss), 1e-12f);
        float xx = dot + btp[0];
        T[b * N_ + n0 + t] = (xx > 0.f) ? (xx + log1pf(expf(-xx)))
                                        : log1pf(expf(xx));
        draw[b * N_ + n0 + t] = 0.f;
    }
    __syncthreads();
    unsigned* fo = (unsigned*)fnT;
    for (int it = 0; it < 16; ++it) {
        int idx = it * 256 + t;
        int nl = idx >> 6, jp = idx & 63;
        float inv = invs[nl];
        fo[(((long)b * N_ + n0 + nl) << 6) + jp] =
            pack_bf2(Ft[2 * jp][nl] * inv, Ft[2 * jp + 1][nl] * inv);
    }
}

// ---------------------------------------------------------------------------
// sim (bf16 MFMA): draw[b][i] += sum_j sigmoid(0.5*(Ti+Tj)*(fn_i . fn_j) + bb)
// ---------------------------------------------------------------------------
__global__ __launch_bounds__(256) void sim_kernel(
    const unsigned short* __restrict__ fnT, const float* __restrict__ T,
    const float* __restrict__ bb, float* __restrict__ draw)
{
    __shared__ unsigned short As[64 * 136];
    __shared__ unsigned short Bs[64 * 136];
    __shared__ float Ti[64], Tj[64];
    const int b = blockIdx.z, i0 = blockIdx.y * 64, j0 = blockIdx.x * 64;
    const int t = threadIdx.x, lane = t & 63, w = t >> 6;
    const int lrow = lane & 15, kgrp = lane >> 4;
    const unsigned short* fb = fnT + (long)b * N_ * 128;

    if (t < 64) Ti[t] = T[b * N_ + i0 + t];
    else if (t < 128) Tj[t - 64] = T[b * N_ + j0 + (t - 64)];

    const int srow = t >> 4, scol = (t & 15) * 8;
    #pragma unroll
    for (int r = 0; r < 4; ++r) {
        uint4 av = *(const uint4*)(fb + (long)(i0 + r * 16 + srow) * 128 + scol);
        uint4 bv = *(const uint4*)(fb + (long)(j0 + r * 16 + srow) * 128 + scol);
        *(uint4*)((char*)As + (r * 16 + srow) * 272 + scol * 2) = av;
        *(uint4*)((char*)Bs + (r * 16 + srow) * 272 + scol * 2) = bv;
    }
    __syncthreads();

    floatx4 acc[4];
    #pragma unroll
    for (int j = 0; j < 4; ++j) acc[j] = (floatx4)0.0f;
    #pragma unroll
    for (int k0 = 0; k0 < 128; k0 += 32) {
        short8 af = *(const short8*)((const char*)As +
                        (w * 16 + lrow) * 272 + k0 * 2 + kgrp * 16);
        #pragma unroll
        for (int j = 0; j < 4; ++j) {
            short8 bf = *(const short8*)((const char*)Bs +
                            (j * 16 + lrow) * 272 + k0 * 2 + kgrp * 16);
            acc[j] = __builtin_amdgcn_mfma_f32_16x16x32_bf16(af, bf, acc[j], 0, 0, 0);
        }
    }

    const float burstb = bb[0];
    float rs[4] = {0.f, 0.f, 0.f, 0.f};
    #pragma unroll
    for (int j = 0; j < 4; ++j) {
        float Tjv = Tj[j * 16 + lrow];
        #pragma unroll
        for (int r = 0; r < 4; ++r) {
            float Tiv = Ti[w * 16 + kgrp * 4 + r];
            float xarg = 0.5f * (Tiv + Tjv) * acc[j][r] + burstb;
            rs[r] += 1.f / (1.f + expf(-xarg));
        }
    }
    #pragma unroll
    for (int off = 1; off < 16; off <<= 1)
        #pragma unroll
        for (int r = 0; r < 4; ++r) rs[r] += __shfl_xor(rs[r], off);
    if (lrow == 0) {
        #pragma unroll
        for (int r = 0; r < 4; ++r)
            atomicAdd(&draw[b * N_ + i0 + w * 16 + kgrp * 4 + r], rs[r]);
    }
}

// ---------------------------------------------------------------------------
// wn: per-token weight; zeroes agg.
// ---------------------------------------------------------------------------
__global__ __launch_bounds__(256) void wn_kernel(
    const float* __restrict__ draw, const float* __restrict__ bp,
    const float* __restrict__ lamd, float* __restrict__ wn,
    float* __restrict__ agg)
{
    const int id = blockIdx.x * 256 + threadIdx.x;
    float d = powf(draw[id], bp[0]);
    d = fminf(fmaxf(d, 1e-3f), 1e3f);
    float lam = 1.f / (1.f + expf(-lamd[0]));
    wn[id] = (1.f - lam) + lam / (d + 1e-6f);
    for (int i = id; i < B_ * L_ * M_; i += B_ * N_) agg[i] = 0.f;
}

// ---------------------------------------------------------------------------
// agg: agg[b][l][m] = sum_n f[l][n] * (1088 a[m] exp(p[m][n]) b[n] wn[n])
// P materialization fused into the Pch load.
// ---------------------------------------------------------------------------
__global__ __launch_bounds__(256) void agg_kernel(
    const float* __restrict__ f, const float* __restrict__ praw,
    const float* __restrict__ avec, const float* __restrict__ bvec,
    const float* __restrict__ wn, float* __restrict__ agg)
{
    __shared__ float fch[L_][65];
    __shared__ float Pch[M_][65];
    __shared__ float a_s[M_], cf[64];
    const int b = blockIdx.y, n0 = blockIdx.x * 64;
    const int t = threadIdx.x, tx = t & 15, ty = t >> 4;
    const float* fb = f + (long)b * L_ * N_;
    const float* Pb = praw + (long)b * M_ * N_;

    if (t < 64) {
        a_s[t] = avec[b * (M_ + 1) + t] * 1088.f;
        cf[t]  = bvec[b * N_ + n0 + t] * wn[b * N_ + n0 + t];
    }
    __syncthreads();

    for (int idx = t; idx < L_ * 64; idx += 256) {
        int l = idx >> 6, c = idx & 63;
        fch[l][c] = fb[(long)l * N_ + n0 + c];
    }
    for (int idx = t; idx < M_ * 64; idx += 256) {
        int m = idx >> 6, c = idx & 63;
        Pch[m][c] = expf(Pb[(long)m * N_ + n0 + c]) * a_s[m] * cf[c];
    }
    __syncthreads();

    float acc[8][4] = {};
    for (int n = 0; n < 64; ++n) {
        float fv[8], pv[4];
        #pragma unroll
        for (int i = 0; i < 8; ++i) fv[i] = fch[ty + 16 * i][n];
        #pragma unroll
        for (int j = 0; j < 4; ++j) pv[j] = Pch[tx * 4 + j][n];
        #pragma unroll
        for (int i = 0; i < 8; ++i)
            #pragma unroll
            for (int j = 0; j < 4; ++j)
                acc[i][j] = fmaf(fv[i], pv[j], acc[i][j]);
    }
    #pragma unroll
    for (int i = 0; i < 8; ++i)
        #pragma unroll
        for (int j = 0; j < 4; ++j)
            atomicAdd(&agg[((long)b * L_ + (ty + 16 * i)) * M_ + tx * 4 + j],
                      acc[i][j]);
}

// ---------------------------------------------------------------------------
// final: per-cluster l2norm over L, concat [tok_n, agg_n], global l2norm.
// ---------------------------------------------------------------------------
__global__ __launch_bounds__(256) void final_kernel(
    const float* __restrict__ tokn, const float* __restrict__ agg,
    float* __restrict__ out)
{
    __shared__ float invm[M_];
    __shared__ float red[4];
    __shared__ float s_invtot;
    const int b = blockIdx.x, t = threadIdx.x;
    const float* ab = agg + (long)b * L_ * M_;

    if (t < 64) {
        float ss = 0.f;
        for (int l = 0; l < L_; ++l) {
            float v = ab[l * M_ + t];
            ss = fmaf(v, v, ss);
        }
        invm[t] = 1.f / fmaxf(sqrtf(ss), 1e-12f);
    }
    __syncthreads();

    float part;
    {
        float tn = tokn[b * G_ + t];
        part = tn * tn;
    }
    for (int idx = t; idx < L_ * M_; idx += 256) {
        float v = ab[idx] * invm[idx & 63];
        part = fmaf(v, v, part);
    }
    for (int off = 32; off; off >>= 1) part += __shfl_down(part, off);
    if ((t & 63) == 0) red[t >> 6] = part;
    __syncthreads();
    if (t == 0)
        s_invtot = 1.f / fmaxf(sqrtf(red[0] + red[1] + red[2] + red[3]), 1e-12f);
    __syncthreads();

    const float invtot = s_invtot;
    float* ob = out + (long)b * (G_ + L_ * M_);
    ob[t] = tokn[b * G_ + t] * invtot;
    for (int idx = t; idx < L_ * M_; idx += 256)
        ob[G_ + idx] = ab[idx] * invm[idx & 63] * invtot;
}

// ---------------------------------------------------------------------------
extern "C" void kernel_launch(void* const* d_in, const int* in_sizes, int n_in,
                              void* d_out, int out_size, void* d_ws, size_t ws_size,
                              hipStream_t stream)
{
    const float* x    = (const float*)d_in[0];
    const float* t_in = (const float*)d_in[1];
    const float* Wt1  = (const float*)d_in[2];
    const float* bt1  = (const float*)d_in[3];
    const float* Wt2  = (const float*)d_in[4];
    const float* bt2  = (const float*)d_in[5];
    const float* Wc1  = (const float*)d_in[6];
    const float* bc1  = (const float*)d_in[7];
    const float* Wc2  = (const float*)d_in[8];
    const float* bc2  = (const float*)d_in[9];
    const float* Ws1  = (const float*)d_in[10];
    const float* bs1  = (const float*)d_in[11];
    const float* Ws2  = (const float*)d_in[12];
    const float* bs2  = (const float*)d_in[13];
    const float* Wtp  = (const float*)d_in[14];
    const float* btp  = (const float*)d_in[15];
    const float* dust = (const float*)d_in[16];
    const float* bb   = (const float*)d_in[17];
    const float* bp   = (const float*)d_in[18];
    const float* lamd = (const float*)d_in[19];

    char* wsb = (char*)d_ws;
    // region 0..25,165,824: xT (8 batches, bf16) during gemm1; then reused:
    unsigned short* xT  = (unsigned short*)wsb;                 // 25,165,824 B
    float* f    = (float*)(wsb + 0);                            //  8,388,608 B
    float* p    = (float*)(wsb + 8388608);                      //  4,194,304 B
    unsigned short* fnT = (unsigned short*)(wsb + 12582912);    //  4,194,304 B
    float* hid  = (float*)(wsb + 16777216);                     //     32,768 B
    float* tok  = (float*)(wsb + 16809984);                     //     16,384 B
    float* tokn = (float*)(wsb + 16826368);                     //     16,384 B
    float* T    = (float*)(wsb + 16842752);                     //     65,536 B
    float* draw = (float*)(wsb + 16908288);                     //     65,536 B
    float* wgt  = (float*)(wsb + 16973824);                     //     65,536 B
    float* agg  = (float*)(wsb + 17039360);                     //    524,288 B
    float* avec = (float*)(wsb + 17563648);                     //      4,160 B
    float* bvec = (float*)(wsb + 17567808);                     //     65,536 B
    unsigned short* hT  = (unsigned short*)(wsb + 25165824);    // 33,554,432 B
    unsigned short* Wbf = (unsigned short*)(wsb + 58720256);    //  3,145,728 B
    unsigned short* W2  = (unsigned short*)(wsb + 61865984);    //    393,216 B
    float* out  = (float*)d_out;

    cast_w_kernel<<<6912, 256, 0, stream>>>(Wc1, Ws1, Wc2, Ws2, Wbf, W2);

    // first layer: transpose+cast x (8 batches at a time), then MFMA GEMM
    xt_kernel   <<<dim3(16, 24, 8), 256, 0, stream>>>(x, xT, 0);
    gemm1_kernel<<<dim3(8, 8, 8), 256, 0, stream>>>(Wbf, xT, bc1, bs1, hT, 0);
    xt_kernel   <<<dim3(16, 24, 8), 256, 0, stream>>>(x, xT, 8);
    gemm1_kernel<<<dim3(8, 8, 8), 256, 0, stream>>>(Wbf, xT, bc1, bs1, hT, 8);

    gemm23_kernel<<<dim3(8, 3, 16), 256, 0, stream>>>(W2, hT, bc2, bs2, f, p);

    token1_kernel<<<dim3(128, 16), 256, 0, stream>>>(t_in, Wt1, bt1, hid);
    token2_kernel<<<dim3(64, 16), 256, 0, stream>>>(hid, Wt2, bt2, tok);
    token3_kernel<<<16, 256, 0, stream>>>(tok, tokn);

    // linear-domain Sinkhorn: 3 x (u-update, v-update)
    ku_kernel<true> <<<dim3(17, 16), 256, 0, stream>>>(p, dust, bvec, avec);
    kv_kernel       <<<dim3(4, 16), 256, 0, stream>>>(p, dust, avec, bvec);
    ku_kernel<false><<<dim3(17, 16), 256, 0, stream>>>(p, dust, bvec, avec);
    kv_kernel       <<<dim3(4, 16), 256, 0, stream>>>(p, dust, avec, bvec);
    ku_kernel<false><<<dim3(17, 16), 256, 0, stream>>>(p, dust, bvec, avec);
    kv_kernel       <<<dim3(4, 16), 256, 0, stream>>>(p, dust, avec, bvec);

    tnorm_kernel<<<dim3(16, 16), 256, 0, stream>>>(f, Wtp, btp, fnT, T, draw);
    sim_kernel  <<<dim3(16, 16, 16), 256, 0, stream>>>(fnT, T, bb, draw);
    wn_kernel   <<<64, 256, 0, stream>>>(draw, bp, lamd, wgt, agg);
    agg_kernel  <<<dim3(16, 16), 256, 0, stream>>>(f, p, avec, bvec, wgt, agg);
    final_kernel<<<16, 256, 0, stream>>>(tokn, agg, out);
}

// Round 5
// 390.970 us; speedup vs baseline: 3.4711x; 1.0478x over previous
//
#include <hip/hip_runtime.h>
#include <math.h>

#define B_   16
#define C_   1536
#define N_   1024
#define M_   64
#define L_   128
#define G_   256
#define HID_ 512

typedef __attribute__((ext_vector_type(8))) short short8;
typedef __attribute__((ext_vector_type(4))) float floatx4;

// round-to-nearest-even fp32 -> bf16
__device__ __forceinline__ unsigned short f2bf_rne(float x) {
    unsigned u = __float_as_uint(x);
    unsigned r = u + 0x7fffu + ((u >> 16) & 1u);
    return (unsigned short)(r >> 16);
}
// round-half-up packed pair (cheap, hot path)
__device__ __forceinline__ unsigned pack_bf2(float lo, float hi) {
    unsigned a = __float_as_uint(lo) + 0x8000u;
    unsigned b = __float_as_uint(hi) + 0x8000u;
    return (a >> 16) | (b & 0xffff0000u);
}

__device__ __forceinline__ void gl2lds16(const void* g, void* l) {
    __builtin_amdgcn_global_load_lds(
        (const __attribute__((address_space(1))) void*)g,
        (__attribute__((address_space(3))) void*)l, 16, 0, 0);
}

// ---------------------------------------------------------------------------
// Weight cast: Wbf[1024][1536] = stack(Wc1,Ws1) bf16;
// W2[192][1024] = [Wc2 | 0 ; 0 | Ws2] bf16 (zero-padded stack).
// ---------------------------------------------------------------------------
__global__ __launch_bounds__(256) void cast_w_kernel(
    const float* __restrict__ Wc1, const float* __restrict__ Ws1,
    const float* __restrict__ Wc2, const float* __restrict__ Ws2,
    unsigned short* __restrict__ Wbf, unsigned short* __restrict__ W2)
{
    const int T1 = 1024 * 1536;
    int idx = blockIdx.x * 256 + threadIdx.x;
    if (idx < T1) {
        float v = (idx < 512 * 1536) ? Wc1[idx] : Ws1[idx - 512 * 1536];
        Wbf[idx] = f2bf_rne(v);
    } else if (idx < T1 + 192 * 1024) {
        int i2 = idx - T1;
        int row = i2 >> 10, k = i2 & 1023;
        float v = 0.f;
        if (row < 128) { if (k < 512) v = Wc2[row * 512 + k]; }
        else           { if (k >= 512) v = Ws2[(row - 128) * 512 + (k - 512)]; }
        W2[i2] = f2bf_rne(v);
    }
}

// ---------------------------------------------------------------------------
// Transpose+cast: xT[b][n][c] bf16 <- x[b][c][n] fp32. 64x64 LDS tile.
// ---------------------------------------------------------------------------
__global__ __launch_bounds__(256) void xt_kernel(
    const float* __restrict__ x, unsigned short* __restrict__ xT)
{
    __shared__ float Xs[64][65];
    const int t = threadIdx.x;
    const int n0 = blockIdx.x * 64, c0 = blockIdx.y * 64, b = blockIdx.z;
    const float* xb = x + (long)b * C_ * N_;
    #pragma unroll
    for (int it = 0; it < 16; ++it) {
        int idx = it * 256 + t, cr = idx >> 6, nc = idx & 63;
        Xs[cr][nc] = xb[(long)(c0 + cr) * N_ + n0 + nc];
    }
    __syncthreads();
    unsigned* xo = (unsigned*)(xT + (long)b * N_ * C_);
    #pragma unroll
    for (int it = 0; it < 8; ++it) {
        int idx = it * 256 + t, nr = idx >> 5, pc = idx & 31;
        xo[(long)(n0 + nr) * 768 + (c0 >> 1) + pc] =
            pack_bf2(Xs[2 * pc][nr], Xs[2 * pc + 1][nr]);
    }
}

// ---------------------------------------------------------------------------
// GEMM1 (bf16 MFMA, m97 structure): hT[b][n][o] = relu(W[o] . xT[b][n] + bias)
// Both operands k-contiguous bf16, staged via global_load_lds dwordx4.
// ---------------------------------------------------------------------------
__global__ __launch_bounds__(256, 2) void gemm1_kernel(
    const unsigned short* __restrict__ Wbf, const unsigned short* __restrict__ xT,
    const float* __restrict__ bc1, const float* __restrict__ bs1,
    unsigned short* __restrict__ hT)
{
    __shared__ unsigned short As[128 * 32];
    __shared__ unsigned short Bs[128 * 32];
    const int t = threadIdx.x;
    const int lane = t & 63, w = t >> 6;
    const int n0 = blockIdx.x * 128, o0 = blockIdx.y * 128, b = blockIdx.z;
    const unsigned short* xb = xT + (long)b * N_ * C_;

    const int wo = (w >> 1) * 64, wn = (w & 1) * 64;
    const int lrow = lane & 15, kgrp = lane >> 4;
    const int arow = t >> 2, acol = (t & 3) * 8;

    floatx4 acc[4][4];
    #pragma unroll
    for (int i = 0; i < 4; ++i)
        #pragma unroll
        for (int j = 0; j < 4; ++j) acc[i][j] = (floatx4)0.0f;

    for (int k0 = 0; k0 < C_; k0 += 32) {
        #pragma unroll
        for (int r = 0; r < 2; ++r)
            gl2lds16(Wbf + (long)(o0 + r * 64 + arow) * C_ + k0 + acol,
                     (char*)As + r * 4096 + t * 16);
        #pragma unroll
        for (int r = 0; r < 2; ++r)
            gl2lds16(xb + (long)(n0 + r * 64 + arow) * C_ + k0 + acol,
                     (char*)Bs + r * 4096 + t * 16);
        __syncthreads();
        short8 af[4], bfr[4];
        #pragma unroll
        for (int i = 0; i < 4; ++i)
            af[i] = *(const short8*)((const char*)As +
                        (wo + i * 16 + lrow) * 64 + kgrp * 16);
        #pragma unroll
        for (int j = 0; j < 4; ++j)
            bfr[j] = *(const short8*)((const char*)Bs +
                        (wn + j * 16 + lrow) * 64 + kgrp * 16);
        #pragma unroll
        for (int i = 0; i < 4; ++i)
            #pragma unroll
            for (int j = 0; j < 4; ++j)
                acc[i][j] = __builtin_amdgcn_mfma_f32_16x16x32_bf16(
                    af[i], bfr[j], acc[i][j], 0, 0, 0);
        __syncthreads();
    }

    const float* bias = (o0 < 512) ? bc1 : bs1;
    const int ob = (o0 < 512) ? o0 : o0 - 512;
    #pragma unroll
    for (int i = 0; i < 4; ++i) {
        int orow = wo + i * 16 + kgrp * 4;
        float b0 = bias[ob + orow + 0], b1 = bias[ob + orow + 1];
        float b2 = bias[ob + orow + 2], b3 = bias[ob + orow + 3];
        #pragma unroll
        for (int j = 0; j < 4; ++j) {
            int n = n0 + wn + j * 16 + lrow;
            float v0 = fmaxf(acc[i][j][0] + b0, 0.f);
            float v1 = fmaxf(acc[i][j][1] + b1, 0.f);
            float v2 = fmaxf(acc[i][j][2] + b2, 0.f);
            float v3 = fmaxf(acc[i][j][3] + b3, 0.f);
            uint2 pk;
            pk.x = ((unsigned)f2bf_rne(v0)) | (((unsigned)f2bf_rne(v1)) << 16);
            pk.y = ((unsigned)f2bf_rne(v2)) | (((unsigned)f2bf_rne(v3)) << 16);
            *(uint2*)&hT[((long)b * N_ + n) * 1024 + o0 + orow] = pk;
        }
    }
}

// ---------------------------------------------------------------------------
// GEMM23 (bf16 MFMA): rows 0-127 -> f fp32, rows 128-191 -> p fp32.
// ---------------------------------------------------------------------------
__global__ __launch_bounds__(256, 2) void gemm23_kernel(
    const unsigned short* __restrict__ W2, const unsigned short* __restrict__ hT,
    const float* __restrict__ bc2, const float* __restrict__ bs2,
    float* __restrict__ f, float* __restrict__ p)
{
    __shared__ unsigned short As[64 * 32];
    __shared__ unsigned short Bs[128 * 32];
    const int t = threadIdx.x;
    const int lane = t & 63, w = t >> 6;
    const int n0 = blockIdx.x * 128, o0 = blockIdx.y * 64, b = blockIdx.z;
    const unsigned short* hTb = hT + (long)b * N_ * 1024;

    const int wo = (w >> 1) * 32, wn = (w & 1) * 64;
    const int lrow = lane & 15, kgrp = lane >> 4;
    const int arow = t >> 2, acol = (t & 3) * 8;

    floatx4 acc[2][4];
    #pragma unroll
    for (int i = 0; i < 2; ++i)
        #pragma unroll
        for (int j = 0; j < 4; ++j) acc[i][j] = (floatx4)0.0f;

    for (int k0 = 0; k0 < 1024; k0 += 32) {
        gl2lds16(W2 + (long)(o0 + arow) * 1024 + k0 + acol, (char*)As + t * 16);
        #pragma unroll
        for (int r = 0; r < 2; ++r)
            gl2lds16(hTb + (long)(n0 + r * 64 + arow) * 1024 + k0 + acol,
                     (char*)Bs + r * 4096 + t * 16);
        __syncthreads();
        short8 af[2], bfr[4];
        #pragma unroll
        for (int i = 0; i < 2; ++i)
            af[i] = *(const short8*)((const char*)As +
                        (wo + i * 16 + lrow) * 64 + kgrp * 16);
        #pragma unroll
        for (int j = 0; j < 4; ++j)
            bfr[j] = *(const short8*)((const char*)Bs +
                        (wn + j * 16 + lrow) * 64 + kgrp * 16);
        #pragma unroll
        for (int i = 0; i < 2; ++i)
            #pragma unroll
            for (int j = 0; j < 4; ++j)
                acc[i][j] = __builtin_amdgcn_mfma_f32_16x16x32_bf16(
                    af[i], bfr[j], acc[i][j], 0, 0, 0);
        __syncthreads();
    }

    #pragma unroll
    for (int i = 0; i < 2; ++i) {
        int o = o0 + wo + i * 16 + kgrp * 4;
        #pragma unroll
        for (int j = 0; j < 4; ++j) {
            int n = n0 + wn + j * 16 + lrow;
            #pragma unroll
            for (int r = 0; r < 4; ++r) {
                int oo = o + r;
                float v = acc[i][j][r];
                if (oo < 128) f[((long)b * L_ + oo) * N_ + n] = v + bc2[oo];
                else p[((long)b * M_ + (oo - 128)) * N_ + n] = v + bs2[oo - 128];
            }
        }
    }
}

// ---------------------------------------------------------------------------
// Token head: wave-per-output GEMV kernels
// ---------------------------------------------------------------------------
__global__ __launch_bounds__(256) void token1_kernel(
    const float* __restrict__ t_in, const float* __restrict__ Wt1,
    const float* __restrict__ bt1, float* __restrict__ hid)
{
    const int lane = threadIdx.x & 63, w = threadIdx.x >> 6;
    const int o = blockIdx.x * 4 + w, b = blockIdx.y;
    const float4* wr = (const float4*)(Wt1 + (long)o * C_);
    const float4* tb = (const float4*)(t_in + (long)b * C_);
    float acc = 0.f;
    #pragma unroll
    for (int i = 0; i < 6; ++i) {
        float4 a = wr[i * 64 + lane], tv = tb[i * 64 + lane];
        acc += a.x * tv.x + a.y * tv.y + a.z * tv.z + a.w * tv.w;
    }
    #pragma unroll
    for (int off = 1; off < 64; off <<= 1) acc += __shfl_xor(acc, off);
    if (lane == 0) hid[b * HID_ + o] = fmaxf(acc + bt1[o], 0.f);
}

__global__ __launch_bounds__(256) void token2_kernel(
    const float* __restrict__ hid, const float* __restrict__ Wt2,
    const float* __restrict__ bt2, float* __restrict__ tok)
{
    const int lane = threadIdx.x & 63, w = threadIdx.x >> 6;
    const int g = blockIdx.x * 4 + w, b = blockIdx.y;
    const float4* wr = (const float4*)(Wt2 + (long)g * HID_);
    const float4* hb = (const float4*)(hid + (long)b * HID_);
    float acc = 0.f;
    #pragma unroll
    for (int i = 0; i < 2; ++i) {
        float4 a = wr[i * 64 + lane], hv = hb[i * 64 + lane];
        acc += a.x * hv.x + a.y * hv.y + a.z * hv.z + a.w * hv.w;
    }
    #pragma unroll
    for (int off = 1; off < 64; off <<= 1) acc += __shfl_xor(acc, off);
    if (lane == 0) tok[b * G_ + g] = acc + bt2[g];
}

__global__ __launch_bounds__(256) void token3_kernel(
    const float* __restrict__ tok, float* __restrict__ tokn)
{
    __shared__ float red[4];
    const int b = blockIdx.x, t = threadIdx.x;
    float v = tok[b * G_ + t];
    float ss = v * v;
    #pragma unroll
    for (int off = 1; off < 64; off <<= 1) ss += __shfl_xor(ss, off);
    if ((t & 63) == 0) red[t >> 6] = ss;
    __syncthreads();
    float inv = 1.f / fmaxf(sqrtf(red[0] + red[1] + red[2] + red[3]), 1e-12f);
    tokn[b * G_ + t] = v * inv;
}

// ---------------------------------------------------------------------------
// Linear-domain Sinkhorn on K = exp(p). ku<true> exponentiates p IN PLACE
// (p becomes K) and computes the first a; later passes are pure FMA.
// a = mu/(K b); b = nu/(K^T a). P = 1088 a K b (materialized only in agg).
// ---------------------------------------------------------------------------
template<bool FIRST>
__global__ __launch_bounds__(256) void ku_kernel(
    float* __restrict__ p, const float* __restrict__ dust,
    const float* __restrict__ bvec, float* __restrict__ avec)
{
    const int t = threadIdx.x, lane = t & 63, w = t >> 6;
    const int m = blockIdx.x * 4 + w, b = blockIdx.y;
    if (m > M_) return;
    const float* bv = bvec + b * N_;
    float s = 0.f;
    if (m < M_) {
        float* row = p + ((long)b * M_ + m) * N_;
        #pragma unroll
        for (int i = 0; i < 16; ++i) {
            int n = i * 64 + lane;
            if (FIRST) {
                float K = expf(row[n]);
                row[n] = K;                 // in-place: p -> K
                s += K;
            } else {
                s += row[n] * bv[n];
            }
        }
    } else {
        float ea = expf(dust[0]);
        if (FIRST) s = 16.f * ea;
        else {
            #pragma unroll
            for (int i = 0; i < 16; ++i) s += bv[i * 64 + lane];
            s *= ea;
        }
    }
    #pragma unroll
    for (int off = 1; off < 64; off <<= 1) s += __shfl_xor(s, off);
    if (lane == 0) {
        float mu = (m < M_) ? (1.f / 1088.f) : (1024.f / 1088.f);
        avec[b * (M_ + 1) + m] = mu / s;
    }
}

__global__ __launch_bounds__(256) void kv_kernel(
    const float* __restrict__ K, const float* __restrict__ dust,
    const float* __restrict__ avec, float* __restrict__ bvec)
{
    __shared__ float a_s[M_ + 1];
    const int t = threadIdx.x, b = blockIdx.y;
    const int n = blockIdx.x * 256 + t;
    if (t < M_ + 1) a_s[t] = avec[b * (M_ + 1) + t];
    __syncthreads();
    float s = expf(dust[0]) * a_s[M_];
    const float* col = K + (long)b * M_ * N_ + n;
    #pragma unroll
    for (int m = 0; m < M_; ++m) s = fmaf(col[(long)m * N_], a_s[m], s);
    bvec[b * N_ + n] = (1.f / 1088.f) / s;
}

// ---------------------------------------------------------------------------
// tnorm: computes T, zeroes draw, writes fnT[b][n][128] bf16 (l2-normalized).
// ---------------------------------------------------------------------------
__global__ __launch_bounds__(256) void tnorm_kernel(
    const float* __restrict__ f, const float* __restrict__ Wtp,
    const float* __restrict__ btp, unsigned short* __restrict__ fnT,
    float* __restrict__ T, float* __restrict__ draw)
{
    __shared__ float Ft[L_][65];
    __shared__ float invs[64];
    __shared__ float wtp_s[L_];
    const int b = blockIdx.y, n0 = blockIdx.x * 64, t = threadIdx.x;
    const float* fb = f + (long)b * L_ * N_;

    if (t < L_) wtp_s[t] = Wtp[t];
    for (int it = 0; it < 32; ++it) {
        int idx = it * 256 + t;
        int l = idx >> 6, c = idx & 63;
        Ft[l][c] = fb[(long)l * N_ + n0 + c];
    }
    __syncthreads();
    if (t < 64) {
        float ss = 0.f, dot = 0.f;
        #pragma unroll
        for (int l = 0; l < L_; ++l) {
            float v = Ft[l][t];
            ss = fmaf(v, v, ss);
            dot = fmaf(v, wtp_s[l], dot);
        }
        invs[t] = 1.f / fmaxf(sqrtf(ss), 1e-12f);
        float xx = dot + btp[0];
        T[b * N_ + n0 + t] = (xx > 0.f) ? (xx + log1pf(expf(-xx)))
                                        : log1pf(expf(xx));
        draw[b * N_ + n0 + t] = 0.f;
    }
    __syncthreads();
    unsigned* fo = (unsigned*)fnT;
    for (int it = 0; it < 16; ++it) {
        int idx = it * 256 + t;
        int nl = idx >> 6, jp = idx & 63;
        float inv = invs[nl];
        fo[(((long)b * N_ + n0 + nl) << 6) + jp] =
            pack_bf2(Ft[2 * jp][nl] * inv, Ft[2 * jp + 1][nl] * inv);
    }
}

// ---------------------------------------------------------------------------
// sim (bf16 MFMA): draw[b][i] += sum_j sigmoid(0.5*(Ti+Tj)*(fn_i . fn_j) + bb)
// i-tile 64, 4 j-tiles of 64 per block: A staged once, atomics once.
// ---------------------------------------------------------------------------
__global__ __launch_bounds__(256) void sim_kernel(
    const unsigned short* __restrict__ fnT, const float* __restrict__ T,
    const float* __restrict__ bb, float* __restrict__ draw)
{
    __shared__ unsigned short As[64 * 136];
    __shared__ unsigned short Bs[64 * 136];
    __shared__ float Ti[64], Tj[64];
    const int b = blockIdx.z, i0 = blockIdx.y * 64, j0base = blockIdx.x * 256;
    const int t = threadIdx.x, lane = t & 63, w = t >> 6;
    const int lrow = lane & 15, kgrp = lane >> 4;
    const unsigned short* fb = fnT + (long)b * N_ * 128;
    const float burstb = bb[0];

    if (t < 64) Ti[t] = T[b * N_ + i0 + t];
    const int srow = t >> 4, scol = (t & 15) * 8;
    #pragma unroll
    for (int r = 0; r < 4; ++r) {
        uint4 av = *(const uint4*)(fb + (long)(i0 + r * 16 + srow) * 128 + scol);
        *(uint4*)((char*)As + (r * 16 + srow) * 272 + scol * 2) = av;
    }

    float rs[4] = {0.f, 0.f, 0.f, 0.f};
    for (int jj = 0; jj < 4; ++jj) {
        const int j0 = j0base + jj * 64;
        __syncthreads();   // As ready (jj=0); Bs/Tj consumers done (jj>0)
        #pragma unroll
        for (int r = 0; r < 4; ++r) {
            uint4 bv = *(const uint4*)(fb + (long)(j0 + r * 16 + srow) * 128 + scol);
            *(uint4*)((char*)Bs + (r * 16 + srow) * 272 + scol * 2) = bv;
        }
        if (t >= 64 && t < 128) Tj[t - 64] = T[b * N_ + j0 + (t - 64)];
        __syncthreads();

        floatx4 acc[4];
        #pragma unroll
        for (int j = 0; j < 4; ++j) acc[j] = (floatx4)0.0f;
        #pragma unroll
        for (int k0 = 0; k0 < 128; k0 += 32) {
            short8 af = *(const short8*)((const char*)As +
                            (w * 16 + lrow) * 272 + k0 * 2 + kgrp * 16);
            #pragma unroll
            for (int j = 0; j < 4; ++j) {
                short8 bf = *(const short8*)((const char*)Bs +
                                (j * 16 + lrow) * 272 + k0 * 2 + kgrp * 16);
                acc[j] = __builtin_amdgcn_mfma_f32_16x16x32_bf16(af, bf, acc[j], 0, 0, 0);
            }
        }
        #pragma unroll
        for (int j = 0; j < 4; ++j) {
            float Tjv = Tj[j * 16 + lrow];
            #pragma unroll
            for (int r = 0; r < 4; ++r) {
                float Tiv = Ti[w * 16 + kgrp * 4 + r];
                float xarg = 0.5f * (Tiv + Tjv) * acc[j][r] + burstb;
                rs[r] += 1.f / (1.f + expf(-xarg));
            }
        }
    }

    #pragma unroll
    for (int off = 1; off < 16; off <<= 1)
        #pragma unroll
        for (int r = 0; r < 4; ++r) rs[r] += __shfl_xor(rs[r], off);
    if (lrow == 0) {
        #pragma unroll
        for (int r = 0; r < 4; ++r)
            atomicAdd(&draw[b * N_ + i0 + w * 16 + kgrp * 4 + r], rs[r]);
    }
}

// ---------------------------------------------------------------------------
// wn: per-token weight; zeroes agg.
// ---------------------------------------------------------------------------
__global__ __launch_bounds__(256) void wn_kernel(
    const float* __restrict__ draw, const float* __restrict__ bp,
    const float* __restrict__ lamd, float* __restrict__ wn,
    float* __restrict__ agg)
{
    const int id = blockIdx.x * 256 + threadIdx.x;
    float d = powf(draw[id], bp[0]);
    d = fminf(fmaxf(d, 1e-3f), 1e3f);
    float lam = 1.f / (1.f + expf(-lamd[0]));
    wn[id] = (1.f - lam) + lam / (d + 1e-6f);
    for (int i = id; i < B_ * L_ * M_; i += B_ * N_) agg[i] = 0.f;
}

// ---------------------------------------------------------------------------
// agg (+ fused final kv): Pch[m][c] = K[m][n0+c]*a[m]; s_c = sum_m Pch + dust;
// scale cf[c] = wn[c]/s_c  (== 1088*b[n]*wn[n]);  agg += f . (Pch*cf).
// ---------------------------------------------------------------------------
__global__ __launch_bounds__(256) void agg_kernel(
    const float* __restrict__ f, const float* __restrict__ Kmat,
    const float* __restrict__ avec, const float* __restrict__ dust,
    const float* __restrict__ wn, float* __restrict__ agg)
{
    __shared__ float fch[L_][65];
    __shared__ float Pch[M_][65];
    __shared__ float a_s[M_ + 1], cf[64];
    const int b = blockIdx.y, n0 = blockIdx.x * 64;
    const int t = threadIdx.x, tx = t & 15, ty = t >> 4;
    const float* fb = f + (long)b * L_ * N_;
    const float* Kb = Kmat + (long)b * M_ * N_;

    if (t < M_ + 1) a_s[t] = avec[b * (M_ + 1) + t];
    __syncthreads();

    for (int idx = t; idx < L_ * 64; idx += 256) {
        int l = idx >> 6, c = idx & 63;
        fch[l][c] = fb[(long)l * N_ + n0 + c];
    }
    for (int idx = t; idx < M_ * 64; idx += 256) {
        int m = idx >> 6, c = idx & 63;
        Pch[m][c] = Kb[(long)m * N_ + n0 + c] * a_s[m];
    }
    __syncthreads();

    if (t < 64) {
        float s = expf(dust[0]) * a_s[M_];
        #pragma unroll
        for (int m = 0; m < M_; ++m) s += Pch[m][t];
        cf[t] = wn[b * N_ + n0 + t] / s;
    }
    __syncthreads();

    float acc[8][4] = {};
    for (int n = 0; n < 64; ++n) {
        float cfn = cf[n];
        float fv[8], pv[4];
        #pragma unroll
        for (int i = 0; i < 8; ++i) fv[i] = fch[ty + 16 * i][n];
        #pragma unroll
        for (int j = 0; j < 4; ++j) pv[j] = Pch[tx * 4 + j][n] * cfn;
        #pragma unroll
        for (int i = 0; i < 8; ++i)
            #pragma unroll
            for (int j = 0; j < 4; ++j)
                acc[i][j] = fmaf(fv[i], pv[j], acc[i][j]);
    }
    #pragma unroll
    for (int i = 0; i < 8; ++i)
        #pragma unroll
        for (int j = 0; j < 4; ++j)
            atomicAdd(&agg[((long)b * L_ + (ty + 16 * i)) * M_ + tx * 4 + j],
                      acc[i][j]);
}

// ---------------------------------------------------------------------------
// final: per-cluster l2norm over L, concat [tok_n, agg_n], global l2norm.
// ---------------------------------------------------------------------------
__global__ __launch_bounds__(256) void final_kernel(
    const float* __restrict__ tokn, const float* __restrict__ agg,
    float* __restrict__ out)
{
    __shared__ float invm[M_];
    __shared__ float red[4];
    __shared__ float s_invtot;
    const int b = blockIdx.x, t = threadIdx.x;
    const float* ab = agg + (long)b * L_ * M_;

    if (t < 64) {
        float ss = 0.f;
        for (int l = 0; l < L_; ++l) {
            float v = ab[l * M_ + t];
            ss = fmaf(v, v, ss);
        }
        invm[t] = 1.f / fmaxf(sqrtf(ss), 1e-12f);
    }
    __syncthreads();

    float part;
    {
        float tn = tokn[b * G_ + t];
        part = tn * tn;
    }
    for (int idx = t; idx < L_ * M_; idx += 256) {
        float v = ab[idx] * invm[idx & 63];
        part = fmaf(v, v, part);
    }
    for (int off = 32; off; off >>= 1) part += __shfl_down(part, off);
    if ((t & 63) == 0) red[t >> 6] = part;
    __syncthreads();
    if (t == 0)
        s_invtot = 1.f / fmaxf(sqrtf(red[0] + red[1] + red[2] + red[3]), 1e-12f);
    __syncthreads();

    const float invtot = s_invtot;
    float* ob = out + (long)b * (G_ + L_ * M_);
    ob[t] = tokn[b * G_ + t] * invtot;
    for (int idx = t; idx < L_ * M_; idx += 256)
        ob[G_ + idx] = ab[idx] * invm[idx & 63] * invtot;
}

// ---------------------------------------------------------------------------
extern "C" void kernel_launch(void* const* d_in, const int* in_sizes, int n_in,
                              void* d_out, int out_size, void* d_ws, size_t ws_size,
                              hipStream_t stream)
{
    const float* x    = (const float*)d_in[0];
    const float* t_in = (const float*)d_in[1];
    const float* Wt1  = (const float*)d_in[2];
    const float* bt1  = (const float*)d_in[3];
    const float* Wt2  = (const float*)d_in[4];
    const float* bt2  = (const float*)d_in[5];
    const float* Wc1  = (const float*)d_in[6];
    const float* bc1  = (const float*)d_in[7];
    const float* Wc2  = (const float*)d_in[8];
    const float* bc2  = (const float*)d_in[9];
    const float* Ws1  = (const float*)d_in[10];
    const float* bs1  = (const float*)d_in[11];
    const float* Ws2  = (const float*)d_in[12];
    const float* bs2  = (const float*)d_in[13];
    const float* Wtp  = (const float*)d_in[14];
    const float* btp  = (const float*)d_in[15];
    const float* dust = (const float*)d_in[16];
    const float* bb   = (const float*)d_in[17];
    const float* bp   = (const float*)d_in[18];
    const float* lamd = (const float*)d_in[19];

    char* wsb = (char*)d_ws;
    // xT: 16 batches bf16, dead after gemm1; f/p/fnT/smalls overlay it after.
    unsigned short* xT  = (unsigned short*)wsb;                 // 50,331,648 B
    float* f    = (float*)(wsb + 0);                            //  8,388,608 B
    float* p    = (float*)(wsb + 8388608);                      //  4,194,304 B
    unsigned short* fnT = (unsigned short*)(wsb + 12582912);    //  4,194,304 B
    float* hid  = (float*)(wsb + 16777216);                     //     32,768 B
    float* tok  = (float*)(wsb + 16809984);                     //     16,384 B
    float* tokn = (float*)(wsb + 16826368);                     //     16,384 B
    float* T    = (float*)(wsb + 16842752);                     //     65,536 B
    float* draw = (float*)(wsb + 16908288);                     //     65,536 B
    float* wgt  = (float*)(wsb + 16973824);                     //     65,536 B
    float* agg  = (float*)(wsb + 17039360);                     //    524,288 B
    float* avec = (float*)(wsb + 17563648);                     //      4,160 B
    float* bvec = (float*)(wsb + 17567808);                     //     65,536 B
    unsigned short* hT  = (unsigned short*)(wsb + 50331648);    // 33,554,432 B
    unsigned short* Wbf = (unsigned short*)(wsb + 83886080);    //  3,145,728 B
    unsigned short* W2  = (unsigned short*)(wsb + 87031808);    //    393,216 B
    float* out  = (float*)d_out;

    cast_w_kernel<<<6912, 256, 0, stream>>>(Wc1, Ws1, Wc2, Ws2, Wbf, W2);

    xt_kernel   <<<dim3(16, 24, 16), 256, 0, stream>>>(x, xT);
    gemm1_kernel<<<dim3(8, 8, 16), 256, 0, stream>>>(Wbf, xT, bc1, bs1, hT);
    gemm23_kernel<<<dim3(8, 3, 16), 256, 0, stream>>>(W2, hT, bc2, bs2, f, p);

    token1_kernel<<<dim3(128, 16), 256, 0, stream>>>(t_in, Wt1, bt1, hid);
    token2_kernel<<<dim3(64, 16), 256, 0, stream>>>(hid, Wt2, bt2, tok);
    token3_kernel<<<16, 256, 0, stream>>>(tok, tokn);

    // linear-domain Sinkhorn (3 iters; last kv fused into agg)
    ku_kernel<true> <<<dim3(17, 16), 256, 0, stream>>>(p, dust, bvec, avec);
    kv_kernel       <<<dim3(4, 16), 256, 0, stream>>>(p, dust, avec, bvec);
    ku_kernel<false><<<dim3(17, 16), 256, 0, stream>>>(p, dust, bvec, avec);
    kv_kernel       <<<dim3(4, 16), 256, 0, stream>>>(p, dust, avec, bvec);
    ku_kernel<false><<<dim3(17, 16), 256, 0, stream>>>(p, dust, bvec, avec);

    tnorm_kernel<<<dim3(16, 16), 256, 0, stream>>>(f, Wtp, btp, fnT, T, draw);
    sim_kernel  <<<dim3(4, 16, 16), 256, 0, stream>>>(fnT, T, bb, draw);
    wn_kernel   <<<64, 256, 0, stream>>>(draw, bp, lamd, wgt, agg);
    agg_kernel  <<<dim3(16, 16), 256, 0, stream>>>(f, p, avec, dust, wgt, agg);
    final_kernel<<<16, 256, 0, stream>>>(tokn, agg, out);
}